// Round 1
// baseline (457.804 us; speedup 1.0000x reference)
//
#include <hip/hip_runtime.h>
#include <hip/hip_bf16.h>
#include <stdint.h>

#define B_ 4
#define T_ 2048
#define C_ 1024
#define H_ 16
#define D_ 64
#define BH_ (B_*H_)
#define M_ (B_*T_)   // 8192 rows

typedef __attribute__((ext_vector_type(8))) short short8;
typedef __attribute__((ext_vector_type(4))) float f32x4;

__device__ __forceinline__ unsigned short f2bf(float f) {
  union { float f; unsigned int u; } v; v.f = f;
  unsigned int r = v.u + 0x7FFFu + ((v.u >> 16) & 1u);   // RNE
  return (unsigned short)(r >> 16);
}

__device__ __forceinline__ void gload_lds16(const void* g, void* l) {
  __builtin_amdgcn_global_load_lds(
      (__attribute__((address_space(1))) void*)g,
      (__attribute__((address_space(3))) void*)l, 16, 0, 0);
}

// ---------------- fp32 -> bf16 convert (vectorized) ----------------
__global__ __launch_bounds__(256) void k_cvt(const float* __restrict__ in,
                                             unsigned short* __restrict__ out, int n) {
  int i = (blockIdx.x * 256 + threadIdx.x) * 4;
  if (i >= n) return;
  float4 v = *reinterpret_cast<const float4*>(in + i);
  union { unsigned short u[4]; unsigned long long ll; } o;
  o.u[0] = f2bf(v.x); o.u[1] = f2bf(v.y); o.u[2] = f2bf(v.z); o.u[3] = f2bf(v.w);
  *reinterpret_cast<unsigned long long*>(out + i) = o.ll;
}

// ---------------- transpose+convert W [K][N] f32 -> Wt [N][K] bf16 ----------------
__global__ __launch_bounds__(256) void k_tr(const float* __restrict__ W,
                                            unsigned short* __restrict__ Wt, int K, int N) {
  __shared__ float t[32][33];
  int n0 = blockIdx.x * 32, k0 = blockIdx.y * 32;
  int tx = threadIdx.x, ty = threadIdx.y;    // (32,8)
  #pragma unroll
  for (int j = 0; j < 4; j++)
    t[ty + j*8][tx] = W[(size_t)(k0 + ty + j*8) * N + n0 + tx];
  __syncthreads();
  #pragma unroll
  for (int j = 0; j < 4; j++)
    Wt[(size_t)(n0 + ty + j*8) * K + k0 + tx] = f2bf(t[tx][ty + j*8]);
}

// ---------------- GEMM: A[M][K] bf16 x Bt[N][K] bf16, m97 structure ----------------
// QKV=1: scatter q/k/v to [B,H,T,D] bf16 with bias.  QKV=0: fp32 out [M][N] + bias.
template<int QKV>
__global__ __launch_bounds__(256) void k_gemm(const unsigned short* __restrict__ A,
                                              const unsigned short* __restrict__ Bt,
                                              const float* __restrict__ bias,
                                              void* __restrict__ outp, int N, int K) {
  __shared__ unsigned short As[128*32];
  __shared__ unsigned short Bs[128*32];
  int tid = threadIdx.x;
  int lane = tid & 63, wave = tid >> 6;
  int lg = lane >> 4, lr = lane & 15;
  int wm = wave >> 1, wn = wave & 1;
  int m0 = blockIdx.y * 128, n0 = blockIdx.x * 128;

  f32x4 acc[4][4];
  #pragma unroll
  for (int i = 0; i < 4; i++)
    #pragma unroll
    for (int j = 0; j < 4; j++) acc[i][j] = (f32x4){0.f, 0.f, 0.f, 0.f};

  for (int kk = 0; kk < K; kk += 32) {
    __syncthreads();
    #pragma unroll
    for (int j = 0; j < 2; j++) {
      int s = tid + j*256;
      int row = s >> 2, g = s & 3;               // 4x 8-elem granules per 32-wide row
      gload_lds16(A  + (size_t)(m0 + row)*K + kk + g*8, As + (size_t)(wave*64 + j*256)*8);
      gload_lds16(Bt + (size_t)(n0 + row)*K + kk + g*8, Bs + (size_t)(wave*64 + j*256)*8);
    }
    __syncthreads();
    short8 a[4], b[4];
    #pragma unroll
    for (int i = 0; i < 4; i++) {
      a[i] = *reinterpret_cast<const short8*>(As + (wm*64 + i*16 + lr)*32 + lg*8);
      b[i] = *reinterpret_cast<const short8*>(Bs + (wn*64 + i*16 + lr)*32 + lg*8);
    }
    #pragma unroll
    for (int i = 0; i < 4; i++)
      #pragma unroll
      for (int j = 0; j < 4; j++)
        acc[i][j] = __builtin_amdgcn_mfma_f32_16x16x32_bf16(a[i], b[j], acc[i][j], 0, 0, 0);
  }

  if (QKV) {
    unsigned short* qb = (unsigned short*)outp;
    const size_t SZ = (size_t)BH_ * T_ * D_;
    #pragma unroll
    for (int i = 0; i < 4; i++) {
      int mb = m0 + wm*64 + i*16 + lg*4;
      #pragma unroll
      for (int j = 0; j < 4; j++) {
        int n = n0 + wn*64 + j*16 + lr;
        float bv = bias[n];
        int which = n >> 10, c = n & 1023, h = c >> 6, d = c & 63;
        unsigned short* base = qb + (size_t)which * SZ;
        #pragma unroll
        for (int r = 0; r < 4; r++) {
          int m = mb + r;
          int bb = m >> 11, t = m & 2047;
          base[((size_t)(bb*H_ + h)*T_ + t)*D_ + d] = f2bf(acc[i][j][r] + bv);
        }
      }
    }
  } else {
    float* out = (float*)outp;
    #pragma unroll
    for (int i = 0; i < 4; i++) {
      int mb = m0 + wm*64 + i*16 + lg*4;
      #pragma unroll
      for (int j = 0; j < 4; j++) {
        int n = n0 + wn*64 + j*16 + lr;
        float bv = bias[n];
        #pragma unroll
        for (int r = 0; r < 4; r++)
          out[(size_t)(mb + r)*N + n] = acc[i][j][r] + bv;
      }
    }
  }
}

// ---------------- flash attention: QT=64 (4 waves x 16 rows), KV-block=32 ----------------
__global__ __launch_bounds__(256) void k_attn(const unsigned short* __restrict__ Qb,
                                              const unsigned short* __restrict__ Kb,
                                              const unsigned short* __restrict__ Vb,
                                              const int* __restrict__ amask,
                                              unsigned short* __restrict__ Yb) {
  __shared__ unsigned short Klds[32*64];      // XOR-swizzled (16B granule ^ (row&7))
  __shared__ unsigned short Vt[64][40];       // V^T, padded stride 40 elems = 80B
  __shared__ unsigned short Plds[4][16][40];  // per-wave P, padded
  __shared__ int msk[32];

  int bh = blockIdx.y;
  int bb = bh >> 4, hh = bh & 15;
  int qbase = blockIdx.x * 64;
  int tid = threadIdx.x;
  int lane = tid & 63, wave = tid >> 6;
  int lg = lane >> 4, lr = lane & 15;

  const unsigned short* Qh = Qb + (size_t)bh * (T_*D_);
  const unsigned short* Kh = Kb + (size_t)bh * (T_*D_);
  const unsigned short* Vh = Vb + (size_t)bh * (T_*D_);

  // Q fragments held in registers for the whole KV loop (A-frag layout)
  int qrow = qbase + wave*16 + lr;
  short8 qf0 = *reinterpret_cast<const short8*>(Qh + (size_t)qrow*D_ + lg*8);
  short8 qf1 = *reinterpret_cast<const short8*>(Qh + (size_t)qrow*D_ + 32 + lg*8);

  f32x4 o[4];
  #pragma unroll
  for (int d = 0; d < 4; d++) o[d] = (f32x4){0.f, 0.f, 0.f, 0.f};
  float mr[4] = {-1e30f, -1e30f, -1e30f, -1e30f};
  float ls[4] = {0.f, 0.f, 0.f, 0.f};

  // staging assignments
  int krow = tid >> 3, kg = tid & 7;
  int ksrcg = kg ^ (krow & 7);                 // pre-swizzled source granule
  int vrow = tid & 31, vd0 = (tid >> 5) * 8;   // lane-permuted so V^T writes spread banks

  int kvend = qbase + 64;
  for (int kv0 = 0; kv0 < kvend; kv0 += 32) {
    __syncthreads();
    // K tile: global_load_lds, linear LDS dest, swizzled source
    gload_lds16(Kh + (size_t)(kv0 + krow)*D_ + ksrcg*8, Klds + (size_t)(wave*64)*8);
    // V tile: regs -> transposed LDS
    short8 vv = *reinterpret_cast<const short8*>(Vh + (size_t)(kv0 + vrow)*D_ + vd0);
    #pragma unroll
    for (int j = 0; j < 8; j++) Vt[vd0 + j][vrow] = (unsigned short)vv[j];
    if (tid < 32) msk[tid] = amask[bb*T_ + kv0 + tid];
    __syncthreads();

    // S = Q K^T  (16 q-rows x 32 kv-cols per wave)
    f32x4 s0 = (f32x4){0.f,0.f,0.f,0.f}, s1 = (f32x4){0.f,0.f,0.f,0.f};
    #pragma unroll
    for (int ks = 0; ks < 2; ks++) {
      short8 qf = ks ? qf1 : qf0;
      #pragma unroll
      for (int nt = 0; nt < 2; nt++) {
        int kvloc = nt*16 + lr;
        int sw = (ks*64 + lg*16) ^ ((kvloc & 7) << 4);
        short8 bfr = *reinterpret_cast<const short8*>((const char*)Klds + kvloc*128 + sw);
        if (nt == 0) s0 = __builtin_amdgcn_mfma_f32_16x16x32_bf16(qf, bfr, s0, 0, 0, 0);
        else         s1 = __builtin_amdgcn_mfma_f32_16x16x32_bf16(qf, bfr, s1, 0, 0, 0);
      }
    }

    // mask + scale
    bool tail = (kv0 + 32 > qbase);
    float p[2][4];
    #pragma unroll
    for (int nt = 0; nt < 2; nt++) {
      int kvg = kv0 + nt*16 + lr;
      bool mok = (msk[nt*16 + lr] != 0);
      #pragma unroll
      for (int r = 0; r < 4; r++) {
        int qg = qbase + wave*16 + lg*4 + r;
        float sv = nt ? s1[r] : s0[r];
        p[nt][r] = (mok && (!tail || kvg <= qg)) ? sv * 0.125f : -1e30f;
      }
    }
    // row-max over 32 cols (16-lane groups own a row set)
    float pm[4];
    #pragma unroll
    for (int r = 0; r < 4; r++) pm[r] = fmaxf(p[0][r], p[1][r]);
    #pragma unroll
    for (int sh = 1; sh < 16; sh <<= 1)
      #pragma unroll
      for (int r = 0; r < 4; r++) pm[r] = fmaxf(pm[r], __shfl_xor(pm[r], sh));

    float rs[4];
    #pragma unroll
    for (int r = 0; r < 4; r++) {
      float mnew = fmaxf(mr[r], pm[r]);
      float corr = __expf(mr[r] - mnew);
      mr[r] = mnew;
      ls[r] *= corr;
      float p0 = __expf(p[0][r] - mnew);
      float p1 = __expf(p[1][r] - mnew);
      rs[r] = p0 + p1;
      #pragma unroll
      for (int d = 0; d < 4; d++) o[d][r] *= corr;
      Plds[wave][lg*4 + r][lr]      = f2bf(p0);
      Plds[wave][lg*4 + r][16 + lr] = f2bf(p1);
    }
    #pragma unroll
    for (int sh = 1; sh < 16; sh <<= 1)
      #pragma unroll
      for (int r = 0; r < 4; r++) rs[r] += __shfl_xor(rs[r], sh);
    #pragma unroll
    for (int r = 0; r < 4; r++) ls[r] += rs[r];

    // O += P V   (P A-frag from own-wave LDS region; no barrier needed)
    short8 pa = *reinterpret_cast<const short8*>(&Plds[wave][lr][lg*8]);
    #pragma unroll
    for (int d = 0; d < 4; d++) {
      short8 vb = *reinterpret_cast<const short8*>(&Vt[d*16 + lr][lg*8]);
      o[d] = __builtin_amdgcn_mfma_f32_16x16x32_bf16(pa, vb, o[d], 0, 0, 0);
    }
  }

  // epilogue: O/l -> Yb [B,T,C] bf16
  #pragma unroll
  for (int r = 0; r < 4; r++) {
    int qg = qbase + wave*16 + lg*4 + r;
    float inv = 1.0f / ls[r];
    #pragma unroll
    for (int d = 0; d < 4; d++)
      Yb[((size_t)bb*T_ + qg)*C_ + hh*D_ + d*16 + lr] = f2bf(o[d][r] * inv);
  }
}

extern "C" void kernel_launch(void* const* d_in, const int* in_sizes, int n_in,
                              void* d_out, int out_size, void* d_ws, size_t ws_size,
                              hipStream_t stream) {
  const float* x      = (const float*)d_in[0];
  const float* W_attn = (const float*)d_in[1];
  const float* b_attn = (const float*)d_in[2];
  const float* W_proj = (const float*)d_in[3];
  const float* b_proj = (const float*)d_in[4];
  const int*   amask  = (const int*)d_in[5];
  float* out = (float*)d_out;

  char* ws = (char*)d_ws;
  size_t off = 0;
  auto alloc = [&](size_t bytes) { char* p = ws + off; off += (bytes + 255) & ~(size_t)255; return p; };
  unsigned short* xb   = (unsigned short*)alloc((size_t)M_ * C_ * 2);        // 16 MiB
  unsigned short* Wta  = (unsigned short*)alloc((size_t)3 * C_ * C_ * 2);    //  6 MiB
  unsigned short* Wtp  = (unsigned short*)alloc((size_t)C_ * C_ * 2);        //  2 MiB
  unsigned short* qkvb = (unsigned short*)alloc((size_t)3 * BH_ * T_ * D_ * 2); // 48 MiB
  unsigned short* Yb   = (unsigned short*)alloc((size_t)M_ * C_ * 2);        // 16 MiB (~88 MiB total)

  k_cvt<<<(M_ * C_) / 1024, 256, 0, stream>>>(x, xb, M_ * C_);
  k_tr<<<dim3(3*C_/32, C_/32), dim3(32, 8), 0, stream>>>(W_attn, Wta, C_, 3*C_);
  k_tr<<<dim3(C_/32,  C_/32),  dim3(32, 8), 0, stream>>>(W_proj, Wtp, C_, C_);

  k_gemm<1><<<dim3(3*C_/128, M_/128), 256, 0, stream>>>(xb, Wta, b_attn, qkvb, 3*C_, C_);

  unsigned short* Qb = qkvb;
  unsigned short* Kb = qkvb + (size_t)BH_ * T_ * D_;
  unsigned short* Vb = qkvb + 2 * (size_t)BH_ * T_ * D_;
  k_attn<<<dim3(T_/64, BH_), 256, 0, stream>>>(Qb, Kb, Vb, amask, Yb);

  k_gemm<0><<<dim3(C_/128, M_/128), 256, 0, stream>>>(Yb, Wtp, b_proj, out, C_, C_);
}

// Round 2
// 308.192 us; speedup vs baseline: 1.4854x; 1.4854x over previous
//
#include <hip/hip_runtime.h>
#include <hip/hip_bf16.h>
#include <stdint.h>

#define B_ 4
#define T_ 2048
#define C_ 1024
#define H_ 16
#define D_ 64
#define BH_ (B_*H_)
#define M_ (B_*T_)   // 8192 rows

typedef __attribute__((ext_vector_type(8))) short short8;
typedef __attribute__((ext_vector_type(4))) float f32x4;
typedef __attribute__((ext_vector_type(16))) float f32x16;

__device__ __forceinline__ unsigned short f2bf(float f) {
  union { float f; unsigned int u; } v; v.f = f;
  unsigned int r = v.u + 0x7FFFu + ((v.u >> 16) & 1u);   // RNE
  return (unsigned short)(r >> 16);
}

__device__ __forceinline__ void gload_lds16(const void* g, void* l) {
  __builtin_amdgcn_global_load_lds(
      (__attribute__((address_space(1))) void*)g,
      (__attribute__((address_space(3))) void*)l, 16, 0, 0);
}

// ---------------- fp32 -> bf16 convert (vectorized) ----------------
__global__ __launch_bounds__(256) void k_cvt(const float* __restrict__ in,
                                             unsigned short* __restrict__ out, int n) {
  int i = (blockIdx.x * 256 + threadIdx.x) * 4;
  if (i >= n) return;
  float4 v = *reinterpret_cast<const float4*>(in + i);
  union { unsigned short u[4]; unsigned long long ll; } o;
  o.u[0] = f2bf(v.x); o.u[1] = f2bf(v.y); o.u[2] = f2bf(v.z); o.u[3] = f2bf(v.w);
  *reinterpret_cast<unsigned long long*>(out + i) = o.ll;
}

// ---------------- transpose+convert W [K][N] f32 -> Wt [N][K] bf16 ----------------
__global__ __launch_bounds__(256) void k_tr(const float* __restrict__ W,
                                            unsigned short* __restrict__ Wt, int K, int N) {
  __shared__ float t[32][33];
  int n0 = blockIdx.x * 32, k0 = blockIdx.y * 32;
  int tx = threadIdx.x, ty = threadIdx.y;    // (32,8)
  #pragma unroll
  for (int j = 0; j < 4; j++)
    t[ty + j*8][tx] = W[(size_t)(k0 + ty + j*8) * N + n0 + tx];
  __syncthreads();
  #pragma unroll
  for (int j = 0; j < 4; j++)
    Wt[(size_t)(n0 + ty + j*8) * K + k0 + tx] = f2bf(t[tx][ty + j*8]);
}

// ---------------- GEMM: A[M][K] bf16 x Bt[N][K] bf16, m97 structure ----------------
template<int QKV>
__global__ __launch_bounds__(256) void k_gemm(const unsigned short* __restrict__ A,
                                              const unsigned short* __restrict__ Bt,
                                              const float* __restrict__ bias,
                                              void* __restrict__ outp, int N, int K) {
  __shared__ unsigned short As[128*32];
  __shared__ unsigned short Bs[128*32];
  int tid = threadIdx.x;
  int lane = tid & 63, wave = tid >> 6;
  int lg = lane >> 4, lr = lane & 15;
  int wm = wave >> 1, wn = wave & 1;
  int m0 = blockIdx.y * 128, n0 = blockIdx.x * 128;

  f32x4 acc[4][4];
  #pragma unroll
  for (int i = 0; i < 4; i++)
    #pragma unroll
    for (int j = 0; j < 4; j++) acc[i][j] = (f32x4){0.f, 0.f, 0.f, 0.f};

  for (int kk = 0; kk < K; kk += 32) {
    __syncthreads();
    #pragma unroll
    for (int j = 0; j < 2; j++) {
      int s = tid + j*256;
      int row = s >> 2, g = s & 3;
      gload_lds16(A  + (size_t)(m0 + row)*K + kk + g*8, As + (size_t)(wave*64 + j*256)*8);
      gload_lds16(Bt + (size_t)(n0 + row)*K + kk + g*8, Bs + (size_t)(wave*64 + j*256)*8);
    }
    __syncthreads();
    short8 a[4], b[4];
    #pragma unroll
    for (int i = 0; i < 4; i++) {
      a[i] = *reinterpret_cast<const short8*>(As + (wm*64 + i*16 + lr)*32 + lg*8);
      b[i] = *reinterpret_cast<const short8*>(Bs + (wn*64 + i*16 + lr)*32 + lg*8);
    }
    #pragma unroll
    for (int i = 0; i < 4; i++)
      #pragma unroll
      for (int j = 0; j < 4; j++)
        acc[i][j] = __builtin_amdgcn_mfma_f32_16x16x32_bf16(a[i], b[j], acc[i][j], 0, 0, 0);
  }

  if (QKV) {
    unsigned short* qb = (unsigned short*)outp;
    const size_t SZ = (size_t)BH_ * T_ * D_;
    #pragma unroll
    for (int i = 0; i < 4; i++) {
      int mb = m0 + wm*64 + i*16 + lg*4;
      #pragma unroll
      for (int j = 0; j < 4; j++) {
        int n = n0 + wn*64 + j*16 + lr;
        float bv = bias[n];
        int which = n >> 10, c = n & 1023, h = c >> 6, d = c & 63;
        unsigned short* base = qb + (size_t)which * SZ;
        #pragma unroll
        for (int r = 0; r < 4; r++) {
          int m = mb + r;
          int bb = m >> 11, t = m & 2047;
          base[((size_t)(bb*H_ + h)*T_ + t)*D_ + d] = f2bf(acc[i][j][r] + bv);
        }
      }
    }
  } else {
    float* out = (float*)outp;
    #pragma unroll
    for (int i = 0; i < 4; i++) {
      int mb = m0 + wm*64 + i*16 + lg*4;
      #pragma unroll
      for (int j = 0; j < 4; j++) {
        int n = n0 + wn*64 + j*16 + lr;
        float bv = bias[n];
        #pragma unroll
        for (int r = 0; r < 4; r++)
          out[(size_t)(mb + r)*N + n] = acc[i][j][r] + bv;
      }
    }
  }
}

// ---------------- flash attention: 4 waves x 32 q-rows, KVB=64, 32x32x16, swapped ----
// S^T = mfma(K, Q): lane owns q = qw + (lane&31); softmax in-register.
// O^T = mfma(V^T, P^T): col = q again -> scalar per-lane rescale.
__global__ __launch_bounds__(256) void k_attn(const unsigned short* __restrict__ Qb,
                                              const unsigned short* __restrict__ Kb,
                                              const unsigned short* __restrict__ Vb,
                                              const int* __restrict__ amask,
                                              unsigned short* __restrict__ Yb) {
  __shared__ unsigned short Kl[2][64*64];   // rows kv(64) x 64d; 16B-granule XOR swizzle
  __shared__ unsigned int   Vt[2][64*32];   // rows d(64) x 64kv bf16 (packed u32), swizzled

  const int bh = blockIdx.y, bb = bh >> 4, hh = bh & 15;
  const int xrev = (int)gridDim.x - 1 - (int)blockIdx.x;   // longest blocks first
  const int qbase = xrev * 128;
  const int tid = threadIdx.x;
  const int lane = tid & 63, w = tid >> 6;
  const int hi = lane >> 5, l31 = lane & 31;
  const int qw = qbase + w * 32;
  const int q  = qw + l31;

  const unsigned short* Qh = Qb + (size_t)bh * (T_*D_);
  const unsigned short* Kh = Kb + (size_t)bh * (T_*D_);
  const unsigned short* Vh = Vb + (size_t)bh * (T_*D_);

  // Q fragments: lane holds Q[q][dt*16 + hi*8 .. +8]
  short8 qf[4];
  #pragma unroll
  for (int dt = 0; dt < 4; ++dt)
    qf[dt] = *reinterpret_cast<const short8*>(Qh + (size_t)q*D_ + dt*16 + hi*8);

  f32x16 o0, o1;
  #pragma unroll
  for (int r = 0; r < 16; ++r) { o0[r] = 0.f; o1[r] = 0.f; }
  float mr = -1e30f, ls = 0.f;

  const int nIter = 2 * xrev + 2;
  const int kvp = tid & 31, d0v = (tid >> 5) * 8;

  auto stage = [&](int it, int nb) {
    int kv0 = it * 64;
    #pragma unroll
    for (int s = 0; s < 2; ++s) {
      int gi = tid + s * 256;
      int row = gi >> 3, gc = gi & 7;
      gload_lds16(Kh + (size_t)(kv0 + row)*D_ + (gc ^ (row & 7)) * 8, &Kl[nb][gi * 8]);
    }
    int kv = kv0 + 2 * kvp;
    short8 v0 = *reinterpret_cast<const short8*>(Vh + (size_t)kv*D_ + d0v);
    short8 v1 = *reinterpret_cast<const short8*>(Vh + (size_t)(kv + 1)*D_ + d0v);
    #pragma unroll
    for (int j = 0; j < 8; ++j) {
      int d = d0v + j;
      unsigned int wd = (unsigned short)v0[j] | ((unsigned int)(unsigned short)v1[j] << 16);
      Vt[nb][d * 32 + (kvp ^ ((d & 7) << 2))] = wd;
    }
  };

  stage(0, 0);
  __syncthreads();
  int buf = 0;

  for (int it = 0; it < nIter; ++it) {
    const int kv0 = it * 64;
    if (it + 1 < nIter) stage(it + 1, buf ^ 1);

    if (kv0 <= qw + 31) {          // wave-uniform: skip fully-causally-masked tiles
      // ---- S^T (2 tiles: kv[0,32) and kv[32,64) x 32 q) ----
      f32x16 st0, st1;
      #pragma unroll
      for (int r = 0; r < 16; ++r) { st0[r] = 0.f; st1[r] = 0.f; }
      #pragma unroll
      for (int dt = 0; dt < 4; ++dt) {
        int g = dt * 2 + hi;
        int ra = l31;
        short8 kf0 = *reinterpret_cast<const short8*>(&Kl[buf][ra*64 + (g ^ (ra & 7)) * 8]);
        st0 = __builtin_amdgcn_mfma_f32_32x32x16_bf16(kf0, qf[dt], st0, 0, 0, 0);
        int rb = 32 + l31;
        short8 kf1 = *reinterpret_cast<const short8*>(&Kl[buf][rb*64 + (g ^ (rb & 7)) * 8]);
        st1 = __builtin_amdgcn_mfma_f32_32x32x16_bf16(kf1, qf[dt], st1, 0, 0, 0);
      }
      #pragma unroll
      for (int r = 0; r < 16; ++r) { st0[r] *= 0.125f; st1[r] *= 0.125f; }

      if (kv0 + 63 > qw) {         // causal masking needed on this tile
        #pragma unroll
        for (int r = 0; r < 16; ++r) {
          int kvl = (r & 3) + 8 * (r >> 2) + 4 * hi;
          if (kv0 + kvl      > q) st0[r] = -1e30f;
          if (kv0 + 32 + kvl > q) st1[r] = -1e30f;
        }
      }
      unsigned long long mb = __ballot(amask[bb*T_ + kv0 + lane] != 0);
      if (mb != ~0ull) {           // pad mask (all-ones fast path)
        #pragma unroll
        for (int r = 0; r < 16; ++r) {
          int kvl = (r & 3) + 8 * (r >> 2) + 4 * hi;
          if (!((mb >> kvl) & 1))        st0[r] = -1e30f;
          if (!((mb >> (kvl + 32)) & 1)) st1[r] = -1e30f;
        }
      }

      // ---- online softmax, fully in-register (one shfl for max, one for sum) ----
      float mm[8];
      #pragma unroll
      for (int r = 0; r < 8; ++r)
        mm[r] = fmaxf(fmaxf(st0[r], st0[r + 8]), fmaxf(st1[r], st1[r + 8]));
      #pragma unroll
      for (int s = 4; s > 0; s >>= 1)
        #pragma unroll
        for (int r = 0; r < s; ++r) mm[r] = fmaxf(mm[r], mm[r + s]);
      float mo = fmaxf(mm[0], __shfl_xor(mm[0], 32));
      float mnew = fmaxf(mr, mo);
      float corr = __expf(mr - mnew);
      mr = mnew;
      float rs = 0.f;
      #pragma unroll
      for (int r = 0; r < 16; ++r) {
        st0[r] = __expf(st0[r] - mnew); rs += st0[r];
        st1[r] = __expf(st1[r] - mnew); rs += st1[r];
      }
      rs += __shfl_xor(rs, 32);
      ls = ls * corr + rs;
      #pragma unroll
      for (int r = 0; r < 16; ++r) { o0[r] *= corr; o1[r] *= corr; }

      // ---- pack P to bf16 pair-words; lane holds kv blocks [8a+4hi, +4) of tile t ----
      unsigned int pw[2][4][2];
      #pragma unroll
      for (int a = 0; a < 4; ++a) {
        pw[0][a][0] = f2bf(st0[4*a])     | ((unsigned int)f2bf(st0[4*a+1]) << 16);
        pw[0][a][1] = f2bf(st0[4*a+2])   | ((unsigned int)f2bf(st0[4*a+3]) << 16);
        pw[1][a][0] = f2bf(st1[4*a])     | ((unsigned int)f2bf(st1[4*a+1]) << 16);
        pw[1][a][1] = f2bf(st1[4*a+2])   | ((unsigned int)f2bf(st1[4*a+3]) << 16);
      }

      // ---- O^T += V^T x P^T over 4 k-slices of 16 kv ----
      #pragma unroll
      for (int kt = 0; kt < 4; ++kt) {
        const int t = kt >> 1, h2 = kt & 1;
        unsigned int send0 = hi ? pw[t][2*h2][0]   : pw[t][2*h2+1][0];
        unsigned int send1 = hi ? pw[t][2*h2][1]   : pw[t][2*h2+1][1];
        unsigned int own0  = hi ? pw[t][2*h2+1][0] : pw[t][2*h2][0];
        unsigned int own1  = hi ? pw[t][2*h2+1][1] : pw[t][2*h2][1];
        unsigned int recv0 = __shfl_xor(send0, 32);
        unsigned int recv1 = __shfl_xor(send1, 32);
        union { unsigned int u[4]; short8 v; } pf;
        pf.u[0] = hi ? recv0 : own0;
        pf.u[1] = hi ? recv1 : own1;
        pf.u[2] = hi ? own0  : recv0;
        pf.u[3] = hi ? own1  : recv1;
        int g = kt * 2 + hi;
        int dA = l31;
        short8 vf0 = *reinterpret_cast<const short8*>(
            (const char*)&Vt[buf][0] + dA*128 + ((g ^ (dA & 7)) * 16));
        o0 = __builtin_amdgcn_mfma_f32_32x32x16_bf16(vf0, pf.v, o0, 0, 0, 0);
        int dB = 32 + l31;
        short8 vf1 = *reinterpret_cast<const short8*>(
            (const char*)&Vt[buf][0] + dB*128 + ((g ^ (dB & 7)) * 16));
        o1 = __builtin_amdgcn_mfma_f32_32x32x16_bf16(vf1, pf.v, o1, 0, 0, 0);
      }
    }
    __syncthreads();
    buf ^= 1;
  }

  // ---- epilogue: lane holds O^T[d][q] for its q; d = 32*dt2 + 8a + 4hi + b ----
  float inv = 1.0f / ls;
  size_t rowbase = ((size_t)bb*T_ + q)*C_ + hh*D_;
  #pragma unroll
  for (int a = 0; a < 4; ++a) {
    union { unsigned short h[4]; unsigned long long ll; } y0, y1;
    #pragma unroll
    for (int bq = 0; bq < 4; ++bq) {
      y0.h[bq] = f2bf(o0[4*a + bq] * inv);
      y1.h[bq] = f2bf(o1[4*a + bq] * inv);
    }
    int d0o = 8*a + 4*hi;
    *reinterpret_cast<unsigned long long*>(Yb + rowbase + d0o)      = y0.ll;
    *reinterpret_cast<unsigned long long*>(Yb + rowbase + 32 + d0o) = y1.ll;
  }
}

extern "C" void kernel_launch(void* const* d_in, const int* in_sizes, int n_in,
                              void* d_out, int out_size, void* d_ws, size_t ws_size,
                              hipStream_t stream) {
  const float* x      = (const float*)d_in[0];
  const float* W_attn = (const float*)d_in[1];
  const float* b_attn = (const float*)d_in[2];
  const float* W_proj = (const float*)d_in[3];
  const float* b_proj = (const float*)d_in[4];
  const int*   amask  = (const int*)d_in[5];
  float* out = (float*)d_out;

  char* ws = (char*)d_ws;
  size_t off = 0;
  auto alloc = [&](size_t bytes) { char* p = ws + off; off += (bytes + 255) & ~(size_t)255; return p; };
  unsigned short* xb   = (unsigned short*)alloc((size_t)M_ * C_ * 2);
  unsigned short* Wta  = (unsigned short*)alloc((size_t)3 * C_ * C_ * 2);
  unsigned short* Wtp  = (unsigned short*)alloc((size_t)C_ * C_ * 2);
  unsigned short* qkvb = (unsigned short*)alloc((size_t)3 * BH_ * T_ * D_ * 2);
  unsigned short* Yb   = (unsigned short*)alloc((size_t)M_ * C_ * 2);

  k_cvt<<<(M_ * C_) / 1024, 256, 0, stream>>>(x, xb, M_ * C_);
  k_tr<<<dim3(3*C_/32, C_/32), dim3(32, 8), 0, stream>>>(W_attn, Wta, C_, 3*C_);
  k_tr<<<dim3(C_/32,  C_/32),  dim3(32, 8), 0, stream>>>(W_proj, Wtp, C_, C_);

  k_gemm<1><<<dim3(3*C_/128, M_/128), 256, 0, stream>>>(xb, Wta, b_attn, qkvb, 3*C_, C_);

  unsigned short* Qb = qkvb;
  unsigned short* Kb = qkvb + (size_t)BH_ * T_ * D_;
  unsigned short* Vb = qkvb + 2 * (size_t)BH_ * T_ * D_;
  k_attn<<<dim3(T_/128, BH_), 256, 0, stream>>>(Qb, Kb, Vb, amask, Yb);

  k_gemm<0><<<dim3(C_/128, M_/128), 256, 0, stream>>>(Yb, Wtp, b_proj, out, C_, C_);
}

// Round 4
// 227.195 us; speedup vs baseline: 2.0150x; 1.3565x over previous
//
#include <hip/hip_runtime.h>
#include <hip/hip_bf16.h>
#include <stdint.h>

#define B_ 4
#define T_ 2048
#define C_ 1024
#define H_ 16
#define D_ 64
#define BH_ (B_*H_)
#define M_ (B_*T_)   // 8192 rows

typedef __attribute__((ext_vector_type(8))) short short8;
typedef __attribute__((ext_vector_type(4))) float f32x4;
typedef __attribute__((ext_vector_type(16))) float f32x16;

#if __has_builtin(__builtin_amdgcn_exp2f)
#define EXP2(x) __builtin_amdgcn_exp2f(x)
#else
#define EXP2(x) exp2f(x)
#endif

__device__ __forceinline__ unsigned short f2bf(float f) {
  union { float f; unsigned int u; } v; v.f = f;
  unsigned int r = v.u + 0x7FFFu + ((v.u >> 16) & 1u);   // RNE
  return (unsigned short)(r >> 16);
}

__device__ __forceinline__ unsigned int cvtpk_bf16(float lo, float hi) {
  unsigned int r;
  asm("v_cvt_pk_bf16_f32 %0, %1, %2" : "=v"(r) : "v"(lo), "v"(hi));
  return r;
}

__device__ __forceinline__ void gload_lds16(const void* g, void* l) {
  __builtin_amdgcn_global_load_lds(
      (__attribute__((address_space(1))) void*)g,
      (__attribute__((address_space(3))) void*)l, 16, 0, 0);
}

// ---------------- fp32 -> bf16 convert (vectorized) ----------------
__global__ __launch_bounds__(256) void k_cvt(const float* __restrict__ in,
                                             unsigned short* __restrict__ out, int n) {
  int i = (blockIdx.x * 256 + threadIdx.x) * 4;
  if (i >= n) return;
  float4 v = *reinterpret_cast<const float4*>(in + i);
  union { unsigned short u[4]; unsigned long long ll; } o;
  o.u[0] = f2bf(v.x); o.u[1] = f2bf(v.y); o.u[2] = f2bf(v.z); o.u[3] = f2bf(v.w);
  *reinterpret_cast<unsigned long long*>(out + i) = o.ll;
}

// ---------------- transpose+convert W [K][N] f32 -> Wt [N][K] bf16 ----------------
__global__ __launch_bounds__(256) void k_tr(const float* __restrict__ W,
                                            unsigned short* __restrict__ Wt, int K, int N) {
  __shared__ float t[32][33];
  int n0 = blockIdx.x * 32, k0 = blockIdx.y * 32;
  int tx = threadIdx.x, ty = threadIdx.y;    // (32,8)
  #pragma unroll
  for (int j = 0; j < 4; j++)
    t[ty + j*8][tx] = W[(size_t)(k0 + ty + j*8) * N + n0 + tx];
  __syncthreads();
  #pragma unroll
  for (int j = 0; j < 4; j++)
    Wt[(size_t)(n0 + ty + j*8) * K + k0 + tx] = f2bf(t[tx][ty + j*8]);
}

// ---------------- GEMM: A[M][K] bf16 x Bt[N][K] bf16, m97 structure ----------------
template<int QKV>
__global__ __launch_bounds__(256) void k_gemm(const unsigned short* __restrict__ A,
                                              const unsigned short* __restrict__ Bt,
                                              const float* __restrict__ bias,
                                              void* __restrict__ outp, int N, int K) {
  __shared__ unsigned short As[128*32];
  __shared__ unsigned short Bs[128*32];
  int tid = threadIdx.x;
  int lane = tid & 63, wave = tid >> 6;
  int lg = lane >> 4, lr = lane & 15;
  int wm = wave >> 1, wn = wave & 1;
  int m0 = blockIdx.y * 128, n0 = blockIdx.x * 128;

  f32x4 acc[4][4];
  #pragma unroll
  for (int i = 0; i < 4; i++)
    #pragma unroll
    for (int j = 0; j < 4; j++) acc[i][j] = (f32x4){0.f, 0.f, 0.f, 0.f};

  for (int kk = 0; kk < K; kk += 32) {
    __syncthreads();
    #pragma unroll
    for (int j = 0; j < 2; j++) {
      int s = tid + j*256;
      int row = s >> 2, g = s & 3;
      gload_lds16(A  + (size_t)(m0 + row)*K + kk + g*8, As + (size_t)(wave*64 + j*256)*8);
      gload_lds16(Bt + (size_t)(n0 + row)*K + kk + g*8, Bs + (size_t)(wave*64 + j*256)*8);
    }
    __syncthreads();
    short8 a[4], b[4];
    #pragma unroll
    for (int i = 0; i < 4; i++) {
      a[i] = *reinterpret_cast<const short8*>(As + (wm*64 + i*16 + lr)*32 + lg*8);
      b[i] = *reinterpret_cast<const short8*>(Bs + (wn*64 + i*16 + lr)*32 + lg*8);
    }
    #pragma unroll
    for (int i = 0; i < 4; i++)
      #pragma unroll
      for (int j = 0; j < 4; j++)
        acc[i][j] = __builtin_amdgcn_mfma_f32_16x16x32_bf16(a[i], b[j], acc[i][j], 0, 0, 0);
  }

  if (QKV) {
    unsigned short* qb = (unsigned short*)outp;
    const size_t SZ = (size_t)BH_ * T_ * D_;
    #pragma unroll
    for (int i = 0; i < 4; i++) {
      int mb = m0 + wm*64 + i*16 + lg*4;
      #pragma unroll
      for (int j = 0; j < 4; j++) {
        int n = n0 + wn*64 + j*16 + lr;
        float bv = bias[n];
        int which = n >> 10, c = n & 1023, h = c >> 6, d = c & 63;
        unsigned short* base = qb + (size_t)which * SZ;
        #pragma unroll
        for (int r = 0; r < 4; r++) {
          int m = mb + r;
          int bb = m >> 11, t = m & 2047;
          base[((size_t)(bb*H_ + h)*T_ + t)*D_ + d] = f2bf(acc[i][j][r] + bv);
        }
      }
    }
  } else {
    float* out = (float*)outp;
    #pragma unroll
    for (int i = 0; i < 4; i++) {
      int mb = m0 + wm*64 + i*16 + lg*4;
      #pragma unroll
      for (int j = 0; j < 4; j++) {
        int n = n0 + wn*64 + j*16 + lr;
        float bv = bias[n];
        #pragma unroll
        for (int r = 0; r < 4; r++)
          out[(size_t)(mb + r)*N + n] = acc[i][j][r] + bv;
      }
    }
  }
}

// ---------------- flash attention, balanced: 8 waves = 2 kv-split groups x 4 waves ----
// Block j handles q-tiles (15-j) then (j): every block does exactly 17 kv-tile iters.
// Group g (waves 4g..4g+3) takes kv-tiles with index%2==g; groups merge (m,l,O) in LDS.
// S^T = mfma(K, Q): lane owns q; softmax in-register (exp2 domain).
__global__ __launch_bounds__(512) void k_attn(const unsigned short* __restrict__ Qb,
                                              const unsigned short* __restrict__ Kb,
                                              const unsigned short* __restrict__ Vb,
                                              const int* __restrict__ amask,
                                              unsigned short* __restrict__ Yb) {
  __shared__ __align__(16) char pool[65536];   // [g][buf][K 8KB | V 8KB]; merge reuses

  const int bh = blockIdx.y, bb = bh >> 4, hh = bh & 15;
  const int jb = blockIdx.x;                    // 0..7
  const int tid = threadIdx.x;
  const int lane = tid & 63, wv = tid >> 6;
  const int g = wv >> 2, w = wv & 3;
  const int hi = lane >> 5, l31 = lane & 31;
  const int tg = tid & 255;

  const float SCALE = 0.125f * 1.44269504088896340736f;  // 1/sqrt(D) * log2(e)

  const unsigned short* Qh = Qb + (size_t)bh * (T_*D_);
  const unsigned short* Kh = Kb + (size_t)bh * (T_*D_);
  const unsigned short* Vh = Vb + (size_t)bh * (T_*D_);

  char* gbase = pool + g * 32768;

  auto stage = [&](int i, int b) {
    const int kv0 = ((i << 1) | g) << 6;
    char* base = gbase + b * 16384;
    #pragma unroll
    for (int s = 0; s < 2; ++s) {
      int gi = tg + s * 256;
      int row = gi >> 3, gc = gi & 7;
      gload_lds16(Kh + (size_t)(kv0 + row)*D_ + (gc ^ (row & 7)) * 8, base + gi * 16);
    }
    int kvp = tg & 31, d0v = (tg >> 5) * 8;
    int kv = kv0 + 2 * kvp;
    short8 v0 = *reinterpret_cast<const short8*>(Vh + (size_t)kv*D_ + d0v);
    short8 v1 = *reinterpret_cast<const short8*>(Vh + (size_t)(kv + 1)*D_ + d0v);
    unsigned int* vt = (unsigned int*)(base + 8192);
    #pragma unroll
    for (int jj = 0; jj < 8; ++jj) {
      int d = d0v + jj;
      unsigned int wd = (unsigned short)v0[jj] | ((unsigned int)(unsigned short)v1[jj] << 16);
      vt[d * 32 + (kvp ^ ((d & 7) << 2))] = wd;
    }
  };

  auto phase = [&](int qtile) {
    const int nT = qtile + 1;                  // kv-tiles per group
    const int qbase = qtile << 7;
    const int qw = qbase + w * 32;
    const int q  = qw + l31;

    short8 qf[4];
    #pragma unroll
    for (int dt = 0; dt < 4; ++dt)
      qf[dt] = *reinterpret_cast<const short8*>(Qh + (size_t)q*D_ + dt*16 + hi*8);

    f32x16 o0, o1;
    #pragma unroll
    for (int r = 0; r < 16; ++r) { o0[r] = 0.f; o1[r] = 0.f; }
    float mr = -1e30f, ls = 0.f;

    stage(0, 0);
    __syncthreads();

    for (int i = 0; i < nT; ++i) {
      const int b = i & 1;
      if (i + 1 < nT) stage(i + 1, b ^ 1);
      const int kv0 = ((i << 1) | g) << 6;

      if (kv0 <= qw + 31) {
        const unsigned short* Klb = (const unsigned short*)(gbase + b * 16384);
        const char* Vtb = gbase + b * 16384 + 8192;

        f32x16 st0, st1;
        #pragma unroll
        for (int r = 0; r < 16; ++r) { st0[r] = 0.f; st1[r] = 0.f; }
        #pragma unroll
        for (int dt = 0; dt < 4; ++dt) {
          int gg = dt * 2 + hi;
          int ra = l31;
          short8 kf0 = *reinterpret_cast<const short8*>(Klb + ra*64 + (gg ^ (ra & 7)) * 8);
          st0 = __builtin_amdgcn_mfma_f32_32x32x16_bf16(kf0, qf[dt], st0, 0, 0, 0);
          int rb = 32 + l31;
          short8 kf1 = *reinterpret_cast<const short8*>(Klb + rb*64 + (gg ^ (rb & 7)) * 8);
          st1 = __builtin_amdgcn_mfma_f32_32x32x16_bf16(kf1, qf[dt], st1, 0, 0, 0);
        }
        #pragma unroll
        for (int r = 0; r < 16; ++r) { st0[r] *= SCALE; st1[r] *= SCALE; }

        if (kv0 + 63 > qw) {
          #pragma unroll
          for (int r = 0; r < 16; ++r) {
            int kvl = (r & 3) + 8 * (r >> 2) + 4 * hi;
            if (kv0 + kvl      > q) st0[r] = -1e30f;
            if (kv0 + 32 + kvl > q) st1[r] = -1e30f;
          }
        }
        unsigned long long mb = __ballot(amask[bb*T_ + kv0 + lane] != 0);
        if (mb != ~0ull) {
          #pragma unroll
          for (int r = 0; r < 16; ++r) {
            int kvl = (r & 3) + 8 * (r >> 2) + 4 * hi;
            if (!((mb >> kvl) & 1))        st0[r] = -1e30f;
            if (!((mb >> (kvl + 32)) & 1)) st1[r] = -1e30f;
          }
        }

        // online softmax in exp2 domain
        float mm[8];
        #pragma unroll
        for (int r = 0; r < 8; ++r)
          mm[r] = fmaxf(fmaxf(st0[r], st0[r + 8]), fmaxf(st1[r], st1[r + 8]));
        #pragma unroll
        for (int s = 4; s > 0; s >>= 1)
          #pragma unroll
          for (int r = 0; r < s; ++r) mm[r] = fmaxf(mm[r], mm[r + s]);
        float mo = fmaxf(mm[0], __shfl_xor(mm[0], 32));
        float mnew = fmaxf(mr, mo);
        float corr = EXP2(mr - mnew);
        mr = mnew;
        float rs = 0.f;
        #pragma unroll
        for (int r = 0; r < 16; ++r) {
          st0[r] = EXP2(st0[r] - mnew); rs += st0[r];
          st1[r] = EXP2(st1[r] - mnew); rs += st1[r];
        }
        rs += __shfl_xor(rs, 32);
        ls = ls * corr + rs;
        #pragma unroll
        for (int r = 0; r < 16; ++r) { o0[r] *= corr; o1[r] *= corr; }

        // pack P to bf16 pair-words
        unsigned int pw[2][4][2];
        #pragma unroll
        for (int a = 0; a < 4; ++a) {
          pw[0][a][0] = cvtpk_bf16(st0[4*a],   st0[4*a+1]);
          pw[0][a][1] = cvtpk_bf16(st0[4*a+2], st0[4*a+3]);
          pw[1][a][0] = cvtpk_bf16(st1[4*a],   st1[4*a+1]);
          pw[1][a][1] = cvtpk_bf16(st1[4*a+2], st1[4*a+3]);
        }

        // O^T += V^T x P^T
        #pragma unroll
        for (int kt = 0; kt < 4; ++kt) {
          const int t = kt >> 1, h2 = kt & 1;
          unsigned int send0 = hi ? pw[t][2*h2][0]   : pw[t][2*h2+1][0];
          unsigned int send1 = hi ? pw[t][2*h2][1]   : pw[t][2*h2+1][1];
          unsigned int own0  = hi ? pw[t][2*h2+1][0] : pw[t][2*h2][0];
          unsigned int own1  = hi ? pw[t][2*h2+1][1] : pw[t][2*h2][1];
          unsigned int recv0 = __shfl_xor(send0, 32);
          unsigned int recv1 = __shfl_xor(send1, 32);
          union { unsigned int u[4]; short8 v; } pf;
          pf.u[0] = hi ? recv0 : own0;
          pf.u[1] = hi ? recv1 : own1;
          pf.u[2] = hi ? own0  : recv0;
          pf.u[3] = hi ? own1  : recv1;
          int gg = kt * 2 + hi;
          int dA = l31;
          short8 vf0 = *reinterpret_cast<const short8*>(Vtb + dA*128 + ((gg ^ (dA & 7)) * 16));
          o0 = __builtin_amdgcn_mfma_f32_32x32x16_bf16(vf0, pf.v, o0, 0, 0, 0);
          int dB = 32 + l31;
          short8 vf1 = *reinterpret_cast<const short8*>(Vtb + dB*128 + ((gg ^ (dB & 7)) * 16));
          o1 = __builtin_amdgcn_mfma_f32_32x32x16_bf16(vf1, pf.v, o1, 0, 0, 0);
        }
      }
      __syncthreads();
    }

    // ---- merge the two kv-split groups via LDS ----
    float* mbuf = (float*)pool;
    const int idx = w * 64 + lane;
    if (g == 1) {
      #pragma unroll
      for (int r = 0; r < 16; ++r) {
        mbuf[idx + r * 256]        = o0[r];
        mbuf[idx + (16 + r) * 256] = o1[r];
      }
      mbuf[idx + 32 * 256] = mr;
      mbuf[idx + 33 * 256] = ls;
    }
    __syncthreads();
    if (g == 0) {
      float m1 = mbuf[idx + 32 * 256], l1 = mbuf[idx + 33 * 256];
      float m = fmaxf(mr, m1);
      float c0 = EXP2(mr - m), c1 = EXP2(m1 - m);
      float inv = 1.0f / (ls * c0 + l1 * c1);
      size_t rowbase = ((size_t)bb*T_ + q)*C_ + hh*D_;
      #pragma unroll
      for (int a = 0; a < 4; ++a) {
        union { unsigned short h[4]; unsigned long long ll; } y0, y1;
        #pragma unroll
        for (int bq = 0; bq < 4; ++bq) {
          int r = 4*a + bq;
          y0.h[bq] = f2bf((o0[r] * c0 + mbuf[idx + r * 256]        * c1) * inv);
          y1.h[bq] = f2bf((o1[r] * c0 + mbuf[idx + (16 + r) * 256] * c1) * inv);
        }
        int d0o = 8*a + 4*hi;
        *reinterpret_cast<unsigned long long*>(Yb + rowbase + d0o)      = y0.ll;
        *reinterpret_cast<unsigned long long*>(Yb + rowbase + 32 + d0o) = y1.ll;
      }
    }
    __syncthreads();
  };

  phase(15 - jb);
  phase(jb);
}

extern "C" void kernel_launch(void* const* d_in, const int* in_sizes, int n_in,
                              void* d_out, int out_size, void* d_ws, size_t ws_size,
                              hipStream_t stream) {
  const float* x      = (const float*)d_in[0];
  const float* W_attn = (const float*)d_in[1];
  const float* b_attn = (const float*)d_in[2];
  const float* W_proj = (const float*)d_in[3];
  const float* b_proj = (const float*)d_in[4];
  const int*   amask  = (const int*)d_in[5];
  float* out = (float*)d_out;

  char* ws = (char*)d_ws;
  size_t off = 0;
  auto alloc = [&](size_t bytes) { char* p = ws + off; off += (bytes + 255) & ~(size_t)255; return p; };
  unsigned short* xb   = (unsigned short*)alloc((size_t)M_ * C_ * 2);
  unsigned short* Wta  = (unsigned short*)alloc((size_t)3 * C_ * C_ * 2);
  unsigned short* Wtp  = (unsigned short*)alloc((size_t)C_ * C_ * 2);
  unsigned short* qkvb = (unsigned short*)alloc((size_t)3 * BH_ * T_ * D_ * 2);
  unsigned short* Yb   = (unsigned short*)alloc((size_t)M_ * C_ * 2);

  k_cvt<<<(M_ * C_) / 1024, 256, 0, stream>>>(x, xb, M_ * C_);
  k_tr<<<dim3(3*C_/32, C_/32), dim3(32, 8), 0, stream>>>(W_attn, Wta, C_, 3*C_);
  k_tr<<<dim3(C_/32,  C_/32),  dim3(32, 8), 0, stream>>>(W_proj, Wtp, C_, C_);

  k_gemm<1><<<dim3(3*C_/128, M_/128), 256, 0, stream>>>(xb, Wta, b_attn, qkvb, 3*C_, C_);

  unsigned short* Qb = qkvb;
  unsigned short* Kb = qkvb + (size_t)BH_ * T_ * D_;
  unsigned short* Vb = qkvb + 2 * (size_t)BH_ * T_ * D_;
  k_attn<<<dim3(8, BH_), 512, 0, stream>>>(Qb, Kb, Vb, amask, Yb);

  k_gemm<0><<<dim3(C_/128, M_/128), 256, 0, stream>>>(Yb, Wtp, b_proj, out, C_, C_);
}

// Round 5
// 220.730 us; speedup vs baseline: 2.0740x; 1.0293x over previous
//
#include <hip/hip_runtime.h>
#include <hip/hip_bf16.h>
#include <stdint.h>

#define B_ 4
#define T_ 2048
#define C_ 1024
#define H_ 16
#define D_ 64
#define BH_ (B_*H_)
#define M_ (B_*T_)   // 8192 rows

typedef __attribute__((ext_vector_type(8))) short short8;
typedef __attribute__((ext_vector_type(4))) float f32x4;
typedef __attribute__((ext_vector_type(16))) float f32x16;

#if __has_builtin(__builtin_amdgcn_exp2f)
#define EXP2(x) __builtin_amdgcn_exp2f(x)
#else
#define EXP2(x) exp2f(x)
#endif

// 1/sqrt(D) * log2(e), folded into Q at QKV-GEMM epilogue
#define QSCALE 0.18033688011112043f

__device__ __forceinline__ unsigned short f2bf(float f) {
  union { float f; unsigned int u; } v; v.f = f;
  unsigned int r = v.u + 0x7FFFu + ((v.u >> 16) & 1u);   // RNE
  return (unsigned short)(r >> 16);
}

__device__ __forceinline__ unsigned int cvtpk_bf16(float lo, float hi) {
  unsigned int r;
  asm("v_cvt_pk_bf16_f32 %0, %1, %2" : "=v"(r) : "v"(lo), "v"(hi));
  return r;
}

__device__ __forceinline__ void gload_lds16(const void* g, void* l) {
  __builtin_amdgcn_global_load_lds(
      (__attribute__((address_space(1))) void*)g,
      (__attribute__((address_space(3))) void*)l, 16, 0, 0);
}

// ---------------- fp32 -> bf16 convert (vectorized) ----------------
__global__ __launch_bounds__(256) void k_cvt(const float* __restrict__ in,
                                             unsigned short* __restrict__ out, int n) {
  int i = (blockIdx.x * 256 + threadIdx.x) * 4;
  if (i >= n) return;
  float4 v = *reinterpret_cast<const float4*>(in + i);
  union { unsigned short u[4]; unsigned long long ll; } o;
  o.u[0] = f2bf(v.x); o.u[1] = f2bf(v.y); o.u[2] = f2bf(v.z); o.u[3] = f2bf(v.w);
  *reinterpret_cast<unsigned long long*>(out + i) = o.ll;
}

// ---------------- transpose+convert W [K][N] f32 -> Wt [N][K] bf16 ----------------
__global__ __launch_bounds__(256) void k_tr(const float* __restrict__ W,
                                            unsigned short* __restrict__ Wt, int K, int N) {
  __shared__ float t[32][33];
  int n0 = blockIdx.x * 32, k0 = blockIdx.y * 32;
  int tx = threadIdx.x, ty = threadIdx.y;    // (32,8)
  #pragma unroll
  for (int j = 0; j < 4; j++)
    t[ty + j*8][tx] = W[(size_t)(k0 + ty + j*8) * N + n0 + tx];
  __syncthreads();
  #pragma unroll
  for (int j = 0; j < 4; j++)
    Wt[(size_t)(n0 + ty + j*8) * K + k0 + tx] = f2bf(t[tx][ty + j*8]);
}

// ---------------- GEMM: A[M][K] bf16 x Bt[N][K] bf16, m97 structure ----------------
template<int QKV>
__global__ __launch_bounds__(256) void k_gemm(const unsigned short* __restrict__ A,
                                              const unsigned short* __restrict__ Bt,
                                              const float* __restrict__ bias,
                                              void* __restrict__ outp, int N, int K) {
  __shared__ unsigned short As[128*32];
  __shared__ unsigned short Bs[128*32];
  int tid = threadIdx.x;
  int lane = tid & 63, wave = tid >> 6;
  int lg = lane >> 4, lr = lane & 15;
  int wm = wave >> 1, wn = wave & 1;
  int m0 = blockIdx.y * 128, n0 = blockIdx.x * 128;

  f32x4 acc[4][4];
  #pragma unroll
  for (int i = 0; i < 4; i++)
    #pragma unroll
    for (int j = 0; j < 4; j++) acc[i][j] = (f32x4){0.f, 0.f, 0.f, 0.f};

  for (int kk = 0; kk < K; kk += 32) {
    __syncthreads();
    #pragma unroll
    for (int j = 0; j < 2; j++) {
      int s = tid + j*256;
      int row = s >> 2, g = s & 3;
      gload_lds16(A  + (size_t)(m0 + row)*K + kk + g*8, As + (size_t)(wave*64 + j*256)*8);
      gload_lds16(Bt + (size_t)(n0 + row)*K + kk + g*8, Bs + (size_t)(wave*64 + j*256)*8);
    }
    __syncthreads();
    short8 a[4], b[4];
    #pragma unroll
    for (int i = 0; i < 4; i++) {
      a[i] = *reinterpret_cast<const short8*>(As + (wm*64 + i*16 + lr)*32 + lg*8);
      b[i] = *reinterpret_cast<const short8*>(Bs + (wn*64 + i*16 + lr)*32 + lg*8);
    }
    #pragma unroll
    for (int i = 0; i < 4; i++)
      #pragma unroll
      for (int j = 0; j < 4; j++)
        acc[i][j] = __builtin_amdgcn_mfma_f32_16x16x32_bf16(a[i], b[j], acc[i][j], 0, 0, 0);
  }

  if (QKV) {
    unsigned short* qb = (unsigned short*)outp;
    const size_t SZ = (size_t)BH_ * T_ * D_;
    #pragma unroll
    for (int i = 0; i < 4; i++) {
      int mb = m0 + wm*64 + i*16 + lg*4;
      #pragma unroll
      for (int j = 0; j < 4; j++) {
        int n = n0 + wn*64 + j*16 + lr;
        float bv = bias[n];
        int which = n >> 10, c = n & 1023, h = c >> 6, d = c & 63;
        unsigned short* base = qb + (size_t)which * SZ;
        #pragma unroll
        for (int r = 0; r < 4; r++) {
          int m = mb + r;
          int bb = m >> 11, t = m & 2047;
          float y = acc[i][j][r] + bv;
          if (which == 0) y *= QSCALE;     // pre-scale Q (fp32, free here)
          base[((size_t)(bb*H_ + h)*T_ + t)*D_ + d] = f2bf(y);
        }
      }
    }
  } else {
    float* out = (float*)outp;
    #pragma unroll
    for (int i = 0; i < 4; i++) {
      int mb = m0 + wm*64 + i*16 + lg*4;
      #pragma unroll
      for (int j = 0; j < 4; j++) {
        int n = n0 + wn*64 + j*16 + lr;
        float bv = bias[n];
        #pragma unroll
        for (int r = 0; r < 4; r++)
          out[(size_t)(mb + r)*N + n] = acc[i][j][r] + bv;
      }
    }
  }
}

// ---------------- flash attention, balanced: 8 waves = 2 kv-split groups x 4 waves ----
// Block j handles q-tiles (15-j) then (j): every block does exactly 17 kv-tile iters.
// Group g (waves 4g..4g+3) takes kv-tiles with index%2==g; groups merge (m,l,O) in LDS.
// S^T = mfma(K, Q): lane owns q; softmax in-register (exp2 domain, Q pre-scaled).
// T14: V loads issued early, LDS writes after compute.  T5: setprio around MFMA.
// T13: defer-max (skip O-rescale when max grows < 2^8).
__global__ __launch_bounds__(512) void k_attn(const unsigned short* __restrict__ Qb,
                                              const unsigned short* __restrict__ Kb,
                                              const unsigned short* __restrict__ Vb,
                                              const int* __restrict__ amask,
                                              unsigned short* __restrict__ Yb) {
  __shared__ __align__(16) char pool[65536];   // [g][buf][K 8KB | V 8KB]; merge reuses

  const int bh = blockIdx.y, bb = bh >> 4, hh = bh & 15;
  const int jb = blockIdx.x;                    // 0..7
  const int tid = threadIdx.x;
  const int lane = tid & 63, wv = tid >> 6;
  const int g = wv >> 2, w = wv & 3;
  const int hi = lane >> 5, l31 = lane & 31;
  const int tg = tid & 255;

  const unsigned short* Qh = Qb + (size_t)bh * (T_*D_);
  const unsigned short* Kh = Kb + (size_t)bh * (T_*D_);
  const unsigned short* Vh = Vb + (size_t)bh * (T_*D_);

  char* gbase = pool + g * 32768;
  const int kvp = tg & 31, d0v = (tg >> 5) * 8;

  // issue K global_load_lds + V/mask global loads for kv-tile i into buf b
  auto stage_load = [&](int i, int b, short8& sv0, short8& sv1, int& nm) {
    const int kv0 = ((i << 1) | g) << 6;
    char* base = gbase + b * 16384;
    #pragma unroll
    for (int s = 0; s < 2; ++s) {
      int gi = tg + s * 256;
      int row = gi >> 3, gc = gi & 7;
      gload_lds16(Kh + (size_t)(kv0 + row)*D_ + (gc ^ (row & 7)) * 8, base + gi * 16);
    }
    int kv = kv0 + 2 * kvp;
    sv0 = *reinterpret_cast<const short8*>(Vh + (size_t)kv*D_ + d0v);
    sv1 = *reinterpret_cast<const short8*>(Vh + (size_t)(kv + 1)*D_ + d0v);
    nm = amask[bb*T_ + kv0 + lane];
  };
  // write V^T (bf16-pair packed, swizzled) into buf b
  auto stage_write = [&](int b, short8 sv0, short8 sv1) {
    unsigned int* vt = (unsigned int*)(gbase + b * 16384 + 8192);
    #pragma unroll
    for (int jj = 0; jj < 8; ++jj) {
      int d = d0v + jj;
      unsigned int wd = (unsigned short)sv0[jj] | ((unsigned int)(unsigned short)sv1[jj] << 16);
      vt[d * 32 + (kvp ^ ((d & 7) << 2))] = wd;
    }
  };

  auto phase = [&](int qtile) {
    const int nT = qtile + 1;                  // kv-tiles per group
    const int qbase = qtile << 7;
    const int qw = qbase + w * 32;
    const int q  = qw + l31;

    short8 qf[4];
    #pragma unroll
    for (int dt = 0; dt < 4; ++dt)
      qf[dt] = *reinterpret_cast<const short8*>(Qh + (size_t)q*D_ + dt*16 + hi*8);

    f32x16 o0, o1;
    #pragma unroll
    for (int r = 0; r < 16; ++r) { o0[r] = 0.f; o1[r] = 0.f; }
    float mr = -1e30f, ls = 0.f;

    short8 sv0, sv1; int cm;
    stage_load(0, 0, sv0, sv1, cm);
    stage_write(0, sv0, sv1);
    __syncthreads();

    for (int i = 0; i < nT; ++i) {
      const int b = i & 1;
      const bool pf = (i + 1 < nT);
      short8 nv0, nv1; int nm = 0;
      if (pf) stage_load(i + 1, b ^ 1, nv0, nv1, nm);   // EARLY: issue loads
      const int kv0 = ((i << 1) | g) << 6;

      if (kv0 <= qw + 31) {
        const unsigned short* Klb = (const unsigned short*)(gbase + b * 16384);
        const char* Vtb = gbase + b * 16384 + 8192;

        f32x16 st0, st1;
        #pragma unroll
        for (int r = 0; r < 16; ++r) { st0[r] = 0.f; st1[r] = 0.f; }
        __builtin_amdgcn_s_setprio(1);
        #pragma unroll
        for (int dt = 0; dt < 4; ++dt) {
          int gg = dt * 2 + hi;
          int ra = l31;
          short8 kf0 = *reinterpret_cast<const short8*>(Klb + ra*64 + (gg ^ (ra & 7)) * 8);
          st0 = __builtin_amdgcn_mfma_f32_32x32x16_bf16(kf0, qf[dt], st0, 0, 0, 0);
          int rb = 32 + l31;
          short8 kf1 = *reinterpret_cast<const short8*>(Klb + rb*64 + (gg ^ (rb & 7)) * 8);
          st1 = __builtin_amdgcn_mfma_f32_32x32x16_bf16(kf1, qf[dt], st1, 0, 0, 0);
        }
        __builtin_amdgcn_s_setprio(0);

        if (kv0 + 63 > qw) {
          #pragma unroll
          for (int r = 0; r < 16; ++r) {
            int kvl = (r & 3) + 8 * (r >> 2) + 4 * hi;
            if (kv0 + kvl      > q) st0[r] = -1e30f;
            if (kv0 + 32 + kvl > q) st1[r] = -1e30f;
          }
        }
        unsigned long long mb = __ballot(cm != 0);
        if (mb != ~0ull) {
          #pragma unroll
          for (int r = 0; r < 16; ++r) {
            int kvl = (r & 3) + 8 * (r >> 2) + 4 * hi;
            if (!((mb >> kvl) & 1))        st0[r] = -1e30f;
            if (!((mb >> (kvl + 32)) & 1)) st1[r] = -1e30f;
          }
        }

        // online softmax (exp2 domain), defer-max rescale (T13)
        float mm[8];
        #pragma unroll
        for (int r = 0; r < 8; ++r)
          mm[r] = fmaxf(fmaxf(st0[r], st0[r + 8]), fmaxf(st1[r], st1[r + 8]));
        #pragma unroll
        for (int s = 4; s > 0; s >>= 1)
          #pragma unroll
          for (int r = 0; r < s; ++r) mm[r] = fmaxf(mm[r], mm[r + s]);
        float mo = fmaxf(mm[0], __shfl_xor(mm[0], 32));
        if (!__all(mo <= mr + 8.0f)) {
          float mnew = fmaxf(mr, mo);
          float corr = EXP2(mr - mnew);
          ls *= corr;
          #pragma unroll
          for (int r = 0; r < 16; ++r) { o0[r] *= corr; o1[r] *= corr; }
          mr = mnew;
        }
        float rs = 0.f;
        #pragma unroll
        for (int r = 0; r < 16; ++r) {
          st0[r] = EXP2(st0[r] - mr); rs += st0[r];
          st1[r] = EXP2(st1[r] - mr); rs += st1[r];
        }
        rs += __shfl_xor(rs, 32);
        ls += rs;

        // pack P to bf16 pair-words
        unsigned int pw[2][4][2];
        #pragma unroll
        for (int a = 0; a < 4; ++a) {
          pw[0][a][0] = cvtpk_bf16(st0[4*a],   st0[4*a+1]);
          pw[0][a][1] = cvtpk_bf16(st0[4*a+2], st0[4*a+3]);
          pw[1][a][0] = cvtpk_bf16(st1[4*a],   st1[4*a+1]);
          pw[1][a][1] = cvtpk_bf16(st1[4*a+2], st1[4*a+3]);
        }

        // O^T += V^T x P^T
        #pragma unroll
        for (int kt = 0; kt < 4; ++kt) {
          const int t = kt >> 1, h2 = kt & 1;
          unsigned int send0 = hi ? pw[t][2*h2][0]   : pw[t][2*h2+1][0];
          unsigned int send1 = hi ? pw[t][2*h2][1]   : pw[t][2*h2+1][1];
          unsigned int own0  = hi ? pw[t][2*h2+1][0] : pw[t][2*h2][0];
          unsigned int own1  = hi ? pw[t][2*h2+1][1] : pw[t][2*h2][1];
          unsigned int recv0 = __shfl_xor(send0, 32);
          unsigned int recv1 = __shfl_xor(send1, 32);
          union { unsigned int u[4]; short8 v; } pf2;
          pf2.u[0] = hi ? recv0 : own0;
          pf2.u[1] = hi ? recv1 : own1;
          pf2.u[2] = hi ? own0  : recv0;
          pf2.u[3] = hi ? own1  : recv1;
          int gg = kt * 2 + hi;
          int dA = l31;
          short8 vf0 = *reinterpret_cast<const short8*>(Vtb + dA*128 + ((gg ^ (dA & 7)) * 16));
          int dB = 32 + l31;
          short8 vf1 = *reinterpret_cast<const short8*>(Vtb + dB*128 + ((gg ^ (dB & 7)) * 16));
          __builtin_amdgcn_s_setprio(1);
          o0 = __builtin_amdgcn_mfma_f32_32x32x16_bf16(vf0, pf2.v, o0, 0, 0, 0);
          o1 = __builtin_amdgcn_mfma_f32_32x32x16_bf16(vf1, pf2.v, o1, 0, 0, 0);
          __builtin_amdgcn_s_setprio(0);
        }
      }
      if (pf) { stage_write(b ^ 1, nv0, nv1); cm = nm; }   // LATE: V writes
      __syncthreads();
    }

    // ---- merge the two kv-split groups via LDS ----
    float* mbuf = (float*)pool;
    const int idx = w * 64 + lane;
    if (g == 1) {
      #pragma unroll
      for (int r = 0; r < 16; ++r) {
        mbuf[idx + r * 256]        = o0[r];
        mbuf[idx + (16 + r) * 256] = o1[r];
      }
      mbuf[idx + 32 * 256] = mr;
      mbuf[idx + 33 * 256] = ls;
    }
    __syncthreads();
    if (g == 0) {
      float m1 = mbuf[idx + 32 * 256], l1 = mbuf[idx + 33 * 256];
      float m = fmaxf(mr, m1);
      float c0 = EXP2(mr - m), c1 = EXP2(m1 - m);
      float inv = 1.0f / (ls * c0 + l1 * c1);
      size_t rowbase = ((size_t)bb*T_ + q)*C_ + hh*D_;
      #pragma unroll
      for (int a = 0; a < 4; ++a) {
        union { unsigned short h[4]; unsigned long long ll; } y0, y1;
        #pragma unroll
        for (int bq = 0; bq < 4; ++bq) {
          int r = 4*a + bq;
          y0.h[bq] = f2bf((o0[r] * c0 + mbuf[idx + r * 256]        * c1) * inv);
          y1.h[bq] = f2bf((o1[r] * c0 + mbuf[idx + (16 + r) * 256] * c1) * inv);
        }
        int d0o = 8*a + 4*hi;
        *reinterpret_cast<unsigned long long*>(Yb + rowbase + d0o)      = y0.ll;
        *reinterpret_cast<unsigned long long*>(Yb + rowbase + 32 + d0o) = y1.ll;
      }
    }
    __syncthreads();
  };

  phase(15 - jb);
  phase(jb);
}

extern "C" void kernel_launch(void* const* d_in, const int* in_sizes, int n_in,
                              void* d_out, int out_size, void* d_ws, size_t ws_size,
                              hipStream_t stream) {
  const float* x      = (const float*)d_in[0];
  const float* W_attn = (const float*)d_in[1];
  const float* b_attn = (const float*)d_in[2];
  const float* W_proj = (const float*)d_in[3];
  const float* b_proj = (const float*)d_in[4];
  const int*   amask  = (const int*)d_in[5];
  float* out = (float*)d_out;

  char* ws = (char*)d_ws;
  size_t off = 0;
  auto alloc = [&](size_t bytes) { char* p = ws + off; off += (bytes + 255) & ~(size_t)255; return p; };
  unsigned short* xb   = (unsigned short*)alloc((size_t)M_ * C_ * 2);
  unsigned short* Wta  = (unsigned short*)alloc((size_t)3 * C_ * C_ * 2);
  unsigned short* Wtp  = (unsigned short*)alloc((size_t)C_ * C_ * 2);
  unsigned short* qkvb = (unsigned short*)alloc((size_t)3 * BH_ * T_ * D_ * 2);
  unsigned short* Yb   = (unsigned short*)alloc((size_t)M_ * C_ * 2);

  k_cvt<<<(M_ * C_) / 1024, 256, 0, stream>>>(x, xb, M_ * C_);
  k_tr<<<dim3(3*C_/32, C_/32), dim3(32, 8), 0, stream>>>(W_attn, Wta, C_, 3*C_);
  k_tr<<<dim3(C_/32,  C_/32),  dim3(32, 8), 0, stream>>>(W_proj, Wtp, C_, C_);

  k_gemm<1><<<dim3(3*C_/128, M_/128), 256, 0, stream>>>(xb, Wta, b_attn, qkvb, 3*C_, C_);

  unsigned short* Qb = qkvb;
  unsigned short* Kb = qkvb + (size_t)BH_ * T_ * D_;
  unsigned short* Vb = qkvb + 2 * (size_t)BH_ * T_ * D_;
  k_attn<<<dim3(8, BH_), 512, 0, stream>>>(Qb, Kb, Vb, amask, Yb);

  k_gemm<0><<<dim3(C_/128, M_/128), 256, 0, stream>>>(Yb, Wtp, b_proj, out, C_, C_);
}

// Round 6
// 203.843 us; speedup vs baseline: 2.2459x; 1.0828x over previous
//
#include <hip/hip_runtime.h>
#include <hip/hip_bf16.h>
#include <stdint.h>

#define B_ 4
#define T_ 2048
#define C_ 1024
#define H_ 16
#define D_ 64
#define BH_ (B_*H_)
#define M_ (B_*T_)   // 8192 rows

typedef __attribute__((ext_vector_type(8))) short short8;
typedef __attribute__((ext_vector_type(4))) float f32x4;
typedef __attribute__((ext_vector_type(16))) float f32x16;

#if __has_builtin(__builtin_amdgcn_exp2f)
#define EXP2(x) __builtin_amdgcn_exp2f(x)
#else
#define EXP2(x) exp2f(x)
#endif

// 1/sqrt(D) * log2(e), folded into Q at QKV-GEMM epilogue
#define QSCALE 0.18033688011112043f

__device__ __forceinline__ unsigned short f2bf(float f) {
  union { float f; unsigned int u; } v; v.f = f;
  unsigned int r = v.u + 0x7FFFu + ((v.u >> 16) & 1u);   // RNE
  return (unsigned short)(r >> 16);
}

__device__ __forceinline__ unsigned int cvtpk_bf16(float lo, float hi) {
  unsigned int r;
  asm("v_cvt_pk_bf16_f32 %0, %1, %2" : "=v"(r) : "v"(lo), "v"(hi));
  return r;
}

__device__ __forceinline__ void gload_lds16(const void* g, void* l) {
  __builtin_amdgcn_global_load_lds(
      (__attribute__((address_space(1))) void*)g,
      (__attribute__((address_space(3))) void*)l, 16, 0, 0);
}

// ---------------- fp32 -> bf16 convert (vectorized) ----------------
__global__ __launch_bounds__(256) void k_cvt(const float* __restrict__ in,
                                             unsigned short* __restrict__ out, int n) {
  int i = (blockIdx.x * 256 + threadIdx.x) * 4;
  if (i >= n) return;
  float4 v = *reinterpret_cast<const float4*>(in + i);
  union { unsigned short u[4]; unsigned long long ll; } o;
  o.u[0] = f2bf(v.x); o.u[1] = f2bf(v.y); o.u[2] = f2bf(v.z); o.u[3] = f2bf(v.w);
  *reinterpret_cast<unsigned long long*>(out + i) = o.ll;
}

// ---------------- transpose+convert W [K][N] f32 -> Wt [N][K] bf16 ----------------
__global__ __launch_bounds__(256) void k_tr(const float* __restrict__ W,
                                            unsigned short* __restrict__ Wt, int K, int N) {
  __shared__ float t[32][33];
  int n0 = blockIdx.x * 32, k0 = blockIdx.y * 32;
  int tx = threadIdx.x, ty = threadIdx.y;    // (32,8)
  #pragma unroll
  for (int j = 0; j < 4; j++)
    t[ty + j*8][tx] = W[(size_t)(k0 + ty + j*8) * N + n0 + tx];
  __syncthreads();
  #pragma unroll
  for (int j = 0; j < 4; j++)
    Wt[(size_t)(n0 + ty + j*8) * K + k0 + tx] = f2bf(t[tx][ty + j*8]);
}

// ---------------- GEMM: A[M][K] bf16 x Bt[N][K] bf16, m97 structure + T1 swizzle ----
template<int QKV>
__global__ __launch_bounds__(256) void k_gemm(const unsigned short* __restrict__ A,
                                              const unsigned short* __restrict__ Bt,
                                              const float* __restrict__ bias,
                                              void* __restrict__ outp, int N, int K) {
  __shared__ unsigned short As[128*32];
  __shared__ unsigned short Bs[128*32];
  int tid = threadIdx.x;
  int lane = tid & 63, wave = tid >> 6;
  int lg = lane >> 4, lr = lane & 15;
  int wm = wave >> 1, wn = wave & 1;

  // T1: XCD-aware chunked remap (grids are multiples of 8)
  int nwg = gridDim.x * gridDim.y;
  int l = blockIdx.y * gridDim.x + blockIdx.x;
  int wg = (l & 7) * (nwg >> 3) + (l >> 3);
  int bx = wg % gridDim.x, by = wg / gridDim.x;
  int m0 = by * 128, n0 = bx * 128;

  f32x4 acc[4][4];
  #pragma unroll
  for (int i = 0; i < 4; i++)
    #pragma unroll
    for (int j = 0; j < 4; j++) acc[i][j] = (f32x4){0.f, 0.f, 0.f, 0.f};

  for (int kk = 0; kk < K; kk += 32) {
    __syncthreads();
    #pragma unroll
    for (int j = 0; j < 2; j++) {
      int s = tid + j*256;
      int row = s >> 2, g = s & 3;
      gload_lds16(A  + (size_t)(m0 + row)*K + kk + g*8, As + (size_t)(wave*64 + j*256)*8);
      gload_lds16(Bt + (size_t)(n0 + row)*K + kk + g*8, Bs + (size_t)(wave*64 + j*256)*8);
    }
    __syncthreads();
    short8 a[4], b[4];
    #pragma unroll
    for (int i = 0; i < 4; i++) {
      a[i] = *reinterpret_cast<const short8*>(As + (wm*64 + i*16 + lr)*32 + lg*8);
      b[i] = *reinterpret_cast<const short8*>(Bs + (wn*64 + i*16 + lr)*32 + lg*8);
    }
    #pragma unroll
    for (int i = 0; i < 4; i++)
      #pragma unroll
      for (int j = 0; j < 4; j++)
        acc[i][j] = __builtin_amdgcn_mfma_f32_16x16x32_bf16(a[i], b[j], acc[i][j], 0, 0, 0);
  }

  if (QKV) {
    unsigned short* qb = (unsigned short*)outp;
    const size_t SZ = (size_t)BH_ * T_ * D_;
    #pragma unroll
    for (int i = 0; i < 4; i++) {
      int mb = m0 + wm*64 + i*16 + lg*4;
      #pragma unroll
      for (int j = 0; j < 4; j++) {
        int n = n0 + wn*64 + j*16 + lr;
        float bv = bias[n];
        int which = n >> 10, c = n & 1023, h = c >> 6, d = c & 63;
        unsigned short* base = qb + (size_t)which * SZ;
        #pragma unroll
        for (int r = 0; r < 4; r++) {
          int m = mb + r;
          int bb = m >> 11, t = m & 2047;
          float y = acc[i][j][r] + bv;
          if (which == 0) y *= QSCALE;     // pre-scale Q (fp32, free here)
          base[((size_t)(bb*H_ + h)*T_ + t)*D_ + d] = f2bf(y);
        }
      }
    }
  } else {
    float* out = (float*)outp;
    #pragma unroll
    for (int i = 0; i < 4; i++) {
      int mb = m0 + wm*64 + i*16 + lg*4;
      #pragma unroll
      for (int j = 0; j < 4; j++) {
        int n = n0 + wn*64 + j*16 + lr;
        float bv = bias[n];
        #pragma unroll
        for (int r = 0; r < 4; r++)
          out[(size_t)(mb + r)*N + n] = acc[i][j][r] + bv;
      }
    }
  }
}

// ---------------- flash attention, balanced: 8 waves = 2 kv-split groups x 4 waves ----
// Logical block wg handles q-tiles (15-jb) then (jb): every block does 17 kv-tile iters.
// T1: wg remapped so each XCD owns 8 consecutive bh (KV working set = 4MB = its L2).
// Group g (waves 4g..4g+3) takes kv-tiles with index%2==g; groups merge (m,l,O) in LDS.
// S^T = mfma(K, Q): lane owns q; softmax in-register (exp2 domain, Q pre-scaled).
// T14: V loads issued early, LDS writes after compute.  T5: setprio around MFMA.
// T13: defer-max (skip O-rescale when max grows < 2^8).
__global__ __launch_bounds__(512) void k_attn(const unsigned short* __restrict__ Qb,
                                              const unsigned short* __restrict__ Kb,
                                              const unsigned short* __restrict__ Vb,
                                              const int* __restrict__ amask,
                                              unsigned short* __restrict__ Yb) {
  __shared__ __align__(16) char pool[65536];   // [g][buf][K 8KB | V 8KB]; merge reuses

  // T1: XCD-aware chunked remap over the 512-block grid
  const int l = blockIdx.y * 8 + blockIdx.x;
  const int wg = (l & 7) * 64 + (l >> 3);
  const int jb = wg & 7;                        // 0..7
  const int bh = wg >> 3;
  const int bb = bh >> 4, hh = bh & 15;

  const int tid = threadIdx.x;
  const int lane = tid & 63, wv = tid >> 6;
  const int g = wv >> 2, w = wv & 3;
  const int hi = lane >> 5, l31 = lane & 31;
  const int tg = tid & 255;

  const unsigned short* Qh = Qb + (size_t)bh * (T_*D_);
  const unsigned short* Kh = Kb + (size_t)bh * (T_*D_);
  const unsigned short* Vh = Vb + (size_t)bh * (T_*D_);

  char* gbase = pool + g * 32768;
  const int kvp = tg & 31, d0v = (tg >> 5) * 8;

  // issue K global_load_lds + V/mask global loads for kv-tile i into buf b
  auto stage_load = [&](int i, int b, short8& sv0, short8& sv1, int& nm) {
    const int kv0 = ((i << 1) | g) << 6;
    char* base = gbase + b * 16384;
    #pragma unroll
    for (int s = 0; s < 2; ++s) {
      int gi = tg + s * 256;
      int row = gi >> 3, gc = gi & 7;
      gload_lds16(Kh + (size_t)(kv0 + row)*D_ + (gc ^ (row & 7)) * 8, base + gi * 16);
    }
    int kv = kv0 + 2 * kvp;
    sv0 = *reinterpret_cast<const short8*>(Vh + (size_t)kv*D_ + d0v);
    sv1 = *reinterpret_cast<const short8*>(Vh + (size_t)(kv + 1)*D_ + d0v);
    nm = amask[bb*T_ + kv0 + lane];
  };
  // write V^T (bf16-pair packed, swizzled) into buf b
  auto stage_write = [&](int b, short8 sv0, short8 sv1) {
    unsigned int* vt = (unsigned int*)(gbase + b * 16384 + 8192);
    #pragma unroll
    for (int jj = 0; jj < 8; ++jj) {
      int d = d0v + jj;
      unsigned int wd = (unsigned short)sv0[jj] | ((unsigned int)(unsigned short)sv1[jj] << 16);
      vt[d * 32 + (kvp ^ ((d & 7) << 2))] = wd;
    }
  };

  auto phase = [&](int qtile) {
    const int nT = qtile + 1;                  // kv-tiles per group
    const int qbase = qtile << 7;
    const int qw = qbase + w * 32;
    const int q  = qw + l31;

    short8 qf[4];
    #pragma unroll
    for (int dt = 0; dt < 4; ++dt)
      qf[dt] = *reinterpret_cast<const short8*>(Qh + (size_t)q*D_ + dt*16 + hi*8);

    f32x16 o0, o1;
    #pragma unroll
    for (int r = 0; r < 16; ++r) { o0[r] = 0.f; o1[r] = 0.f; }
    float mr = -1e30f, ls = 0.f;

    short8 sv0, sv1; int cm;
    stage_load(0, 0, sv0, sv1, cm);
    stage_write(0, sv0, sv1);
    __syncthreads();

    for (int i = 0; i < nT; ++i) {
      const int b = i & 1;
      const bool pf = (i + 1 < nT);
      short8 nv0, nv1; int nm = 0;
      if (pf) stage_load(i + 1, b ^ 1, nv0, nv1, nm);   // EARLY: issue loads
      const int kv0 = ((i << 1) | g) << 6;

      if (kv0 <= qw + 31) {
        const unsigned short* Klb = (const unsigned short*)(gbase + b * 16384);
        const char* Vtb = gbase + b * 16384 + 8192;

        f32x16 st0, st1;
        #pragma unroll
        for (int r = 0; r < 16; ++r) { st0[r] = 0.f; st1[r] = 0.f; }
        __builtin_amdgcn_s_setprio(1);
        #pragma unroll
        for (int dt = 0; dt < 4; ++dt) {
          int gg = dt * 2 + hi;
          int ra = l31;
          short8 kf0 = *reinterpret_cast<const short8*>(Klb + ra*64 + (gg ^ (ra & 7)) * 8);
          st0 = __builtin_amdgcn_mfma_f32_32x32x16_bf16(kf0, qf[dt], st0, 0, 0, 0);
          int rb = 32 + l31;
          short8 kf1 = *reinterpret_cast<const short8*>(Klb + rb*64 + (gg ^ (rb & 7)) * 8);
          st1 = __builtin_amdgcn_mfma_f32_32x32x16_bf16(kf1, qf[dt], st1, 0, 0, 0);
        }
        __builtin_amdgcn_s_setprio(0);

        if (kv0 + 63 > qw) {
          #pragma unroll
          for (int r = 0; r < 16; ++r) {
            int kvl = (r & 3) + 8 * (r >> 2) + 4 * hi;
            if (kv0 + kvl      > q) st0[r] = -1e30f;
            if (kv0 + 32 + kvl > q) st1[r] = -1e30f;
          }
        }
        unsigned long long mb = __ballot(cm != 0);
        if (mb != ~0ull) {
          #pragma unroll
          for (int r = 0; r < 16; ++r) {
            int kvl = (r & 3) + 8 * (r >> 2) + 4 * hi;
            if (!((mb >> kvl) & 1))        st0[r] = -1e30f;
            if (!((mb >> (kvl + 32)) & 1)) st1[r] = -1e30f;
          }
        }

        // online softmax (exp2 domain), defer-max rescale (T13)
        float mm[8];
        #pragma unroll
        for (int r = 0; r < 8; ++r)
          mm[r] = fmaxf(fmaxf(st0[r], st0[r + 8]), fmaxf(st1[r], st1[r + 8]));
        #pragma unroll
        for (int s = 4; s > 0; s >>= 1)
          #pragma unroll
          for (int r = 0; r < s; ++r) mm[r] = fmaxf(mm[r], mm[r + s]);
        float mo = fmaxf(mm[0], __shfl_xor(mm[0], 32));
        if (!__all(mo <= mr + 8.0f)) {
          float mnew = fmaxf(mr, mo);
          float corr = EXP2(mr - mnew);
          ls *= corr;
          #pragma unroll
          for (int r = 0; r < 16; ++r) { o0[r] *= corr; o1[r] *= corr; }
          mr = mnew;
        }
        float rs = 0.f;
        #pragma unroll
        for (int r = 0; r < 16; ++r) {
          st0[r] = EXP2(st0[r] - mr); rs += st0[r];
          st1[r] = EXP2(st1[r] - mr); rs += st1[r];
        }
        rs += __shfl_xor(rs, 32);
        ls += rs;

        // pack P to bf16 pair-words
        unsigned int pw[2][4][2];
        #pragma unroll
        for (int a = 0; a < 4; ++a) {
          pw[0][a][0] = cvtpk_bf16(st0[4*a],   st0[4*a+1]);
          pw[0][a][1] = cvtpk_bf16(st0[4*a+2], st0[4*a+3]);
          pw[1][a][0] = cvtpk_bf16(st1[4*a],   st1[4*a+1]);
          pw[1][a][1] = cvtpk_bf16(st1[4*a+2], st1[4*a+3]);
        }

        // O^T += V^T x P^T
        #pragma unroll
        for (int kt = 0; kt < 4; ++kt) {
          const int t = kt >> 1, h2 = kt & 1;
          unsigned int send0 = hi ? pw[t][2*h2][0]   : pw[t][2*h2+1][0];
          unsigned int send1 = hi ? pw[t][2*h2][1]   : pw[t][2*h2+1][1];
          unsigned int own0  = hi ? pw[t][2*h2+1][0] : pw[t][2*h2][0];
          unsigned int own1  = hi ? pw[t][2*h2+1][1] : pw[t][2*h2][1];
          unsigned int recv0 = __shfl_xor(send0, 32);
          unsigned int recv1 = __shfl_xor(send1, 32);
          union { unsigned int u[4]; short8 v; } pf2;
          pf2.u[0] = hi ? recv0 : own0;
          pf2.u[1] = hi ? recv1 : own1;
          pf2.u[2] = hi ? own0  : recv0;
          pf2.u[3] = hi ? own1  : recv1;
          int gg = kt * 2 + hi;
          int dA = l31;
          short8 vf0 = *reinterpret_cast<const short8*>(Vtb + dA*128 + ((gg ^ (dA & 7)) * 16));
          int dB = 32 + l31;
          short8 vf1 = *reinterpret_cast<const short8*>(Vtb + dB*128 + ((gg ^ (dB & 7)) * 16));
          __builtin_amdgcn_s_setprio(1);
          o0 = __builtin_amdgcn_mfma_f32_32x32x16_bf16(vf0, pf2.v, o0, 0, 0, 0);
          o1 = __builtin_amdgcn_mfma_f32_32x32x16_bf16(vf1, pf2.v, o1, 0, 0, 0);
          __builtin_amdgcn_s_setprio(0);
        }
      }
      if (pf) { stage_write(b ^ 1, nv0, nv1); cm = nm; }   // LATE: V writes
      __syncthreads();
    }

    // ---- merge the two kv-split groups via LDS ----
    float* mbuf = (float*)pool;
    const int idx = w * 64 + lane;
    if (g == 1) {
      #pragma unroll
      for (int r = 0; r < 16; ++r) {
        mbuf[idx + r * 256]        = o0[r];
        mbuf[idx + (16 + r) * 256] = o1[r];
      }
      mbuf[idx + 32 * 256] = mr;
      mbuf[idx + 33 * 256] = ls;
    }
    __syncthreads();
    if (g == 0) {
      float m1 = mbuf[idx + 32 * 256], l1 = mbuf[idx + 33 * 256];
      float m = fmaxf(mr, m1);
      float c0 = EXP2(mr - m), c1 = EXP2(m1 - m);
      float inv = 1.0f / (ls * c0 + l1 * c1);
      size_t rowbase = ((size_t)bb*T_ + q)*C_ + hh*D_;
      #pragma unroll
      for (int a = 0; a < 4; ++a) {
        union { unsigned short h[4]; unsigned long long ll; } y0, y1;
        #pragma unroll
        for (int bq = 0; bq < 4; ++bq) {
          int r = 4*a + bq;
          y0.h[bq] = f2bf((o0[r] * c0 + mbuf[idx + r * 256]        * c1) * inv);
          y1.h[bq] = f2bf((o1[r] * c0 + mbuf[idx + (16 + r) * 256] * c1) * inv);
        }
        int d0o = 8*a + 4*hi;
        *reinterpret_cast<unsigned long long*>(Yb + rowbase + d0o)      = y0.ll;
        *reinterpret_cast<unsigned long long*>(Yb + rowbase + 32 + d0o) = y1.ll;
      }
    }
    __syncthreads();
  };

  phase(15 - jb);
  phase(jb);
}

extern "C" void kernel_launch(void* const* d_in, const int* in_sizes, int n_in,
                              void* d_out, int out_size, void* d_ws, size_t ws_size,
                              hipStream_t stream) {
  const float* x      = (const float*)d_in[0];
  const float* W_attn = (const float*)d_in[1];
  const float* b_attn = (const float*)d_in[2];
  const float* W_proj = (const float*)d_in[3];
  const float* b_proj = (const float*)d_in[4];
  const int*   amask  = (const int*)d_in[5];
  float* out = (float*)d_out;

  char* ws = (char*)d_ws;
  size_t off = 0;
  auto alloc = [&](size_t bytes) { char* p = ws + off; off += (bytes + 255) & ~(size_t)255; return p; };
  unsigned short* xb   = (unsigned short*)alloc((size_t)M_ * C_ * 2);
  unsigned short* Wta  = (unsigned short*)alloc((size_t)3 * C_ * C_ * 2);
  unsigned short* Wtp  = (unsigned short*)alloc((size_t)C_ * C_ * 2);
  unsigned short* qkvb = (unsigned short*)alloc((size_t)3 * BH_ * T_ * D_ * 2);
  unsigned short* Yb   = (unsigned short*)alloc((size_t)M_ * C_ * 2);

  k_cvt<<<(M_ * C_) / 1024, 256, 0, stream>>>(x, xb, M_ * C_);
  k_tr<<<dim3(3*C_/32, C_/32), dim3(32, 8), 0, stream>>>(W_attn, Wta, C_, 3*C_);
  k_tr<<<dim3(C_/32,  C_/32),  dim3(32, 8), 0, stream>>>(W_proj, Wtp, C_, C_);

  k_gemm<1><<<dim3(3*C_/128, M_/128), 256, 0, stream>>>(xb, Wta, b_attn, qkvb, 3*C_, C_);

  unsigned short* Qb = qkvb;
  unsigned short* Kb = qkvb + (size_t)BH_ * T_ * D_;
  unsigned short* Vb = qkvb + 2 * (size_t)BH_ * T_ * D_;
  k_attn<<<dim3(8, BH_), 512, 0, stream>>>(Qb, Kb, Vb, amask, Yb);

  k_gemm<0><<<dim3(C_/128, M_/128), 256, 0, stream>>>(Yb, Wtp, b_proj, out, C_, C_);
}

// Round 7
// 193.684 us; speedup vs baseline: 2.3637x; 1.0525x over previous
//
#include <hip/hip_runtime.h>
#include <hip/hip_bf16.h>
#include <stdint.h>

#define B_ 4
#define T_ 2048
#define C_ 1024
#define H_ 16
#define D_ 64
#define BH_ (B_*H_)
#define M_ (B_*T_)   // 8192 rows

typedef __attribute__((ext_vector_type(8))) short short8;
typedef __attribute__((ext_vector_type(4))) float f32x4;
typedef __attribute__((ext_vector_type(16))) float f32x16;

#if __has_builtin(__builtin_amdgcn_exp2f)
#define EXP2(x) __builtin_amdgcn_exp2f(x)
#else
#define EXP2(x) exp2f(x)
#endif

// 1/sqrt(D) * log2(e), folded into Q at QKV-GEMM epilogue
#define QSCALE 0.18033688011112043f

__device__ __forceinline__ unsigned short f2bf(float f) {
  union { float f; unsigned int u; } v; v.f = f;
  unsigned int r = v.u + 0x7FFFu + ((v.u >> 16) & 1u);   // RNE
  return (unsigned short)(r >> 16);
}

__device__ __forceinline__ unsigned int cvtpk_bf16(float lo, float hi) {
  unsigned int r;
  asm("v_cvt_pk_bf16_f32 %0, %1, %2" : "=v"(r) : "v"(lo), "v"(hi));
  return r;
}

__device__ __forceinline__ void gload_lds16(const void* g, void* l) {
  __builtin_amdgcn_global_load_lds(
      (__attribute__((address_space(1))) void*)g,
      (__attribute__((address_space(3))) void*)l, 16, 0, 0);
}

// ---------------- fp32 -> bf16 convert (vectorized) ----------------
__global__ __launch_bounds__(256) void k_cvt(const float* __restrict__ in,
                                             unsigned short* __restrict__ out, int n) {
  int i = (blockIdx.x * 256 + threadIdx.x) * 4;
  if (i >= n) return;
  float4 v = *reinterpret_cast<const float4*>(in + i);
  union { unsigned short u[4]; unsigned long long ll; } o;
  o.u[0] = f2bf(v.x); o.u[1] = f2bf(v.y); o.u[2] = f2bf(v.z); o.u[3] = f2bf(v.w);
  *reinterpret_cast<unsigned long long*>(out + i) = o.ll;
}

// ---------------- transpose+convert W [K][N] f32 -> Wt [N][K] bf16 ----------------
__global__ __launch_bounds__(256) void k_tr(const float* __restrict__ W,
                                            unsigned short* __restrict__ Wt, int K, int N) {
  __shared__ float t[32][33];
  int n0 = blockIdx.x * 32, k0 = blockIdx.y * 32;
  int tx = threadIdx.x, ty = threadIdx.y;    // (32,8)
  #pragma unroll
  for (int j = 0; j < 4; j++)
    t[ty + j*8][tx] = W[(size_t)(k0 + ty + j*8) * N + n0 + tx];
  __syncthreads();
  #pragma unroll
  for (int j = 0; j < 4; j++)
    Wt[(size_t)(n0 + ty + j*8) * K + k0 + tx] = f2bf(t[tx][ty + j*8]);
}

// ---------------- GEMM, 8-phase counted-vmcnt (T2+T3+T4+T5), BM=128 BN=256 BK=64 ----
// 8 waves = 2M x 4N; per-wave output 64x64 (acc[2][2][2][2] f32x4).
// LDS: double-buffered A[128][64] + B[256][64], XOR-swizzled 16B granules (g ^= row&7),
// staged via global_load_lds with pre-swizzled global source (both-sides rule).
// Per K-tile: 4 phases, each {8 ds_read_b128 | stage 1 half | bar | lgkm0 | 8 MFMA | bar};
// counted vmcnt(3) once per tile (phase 4), never 0 mid-loop.
template<int QKV>
__global__ __launch_bounds__(512) void k_gemm8(const unsigned short* __restrict__ A,
                                               const unsigned short* __restrict__ Bt,
                                               const float* __restrict__ bias,
                                               void* __restrict__ outp, int N, int K) {
  __shared__ __align__(16) unsigned short Al[2][128*64];   // 32 KB
  __shared__ __align__(16) unsigned short Bl[2][256*64];   // 64 KB

  const int tid = threadIdx.x;
  const int lane = tid & 63, wv = tid >> 6;
  const int lg = lane >> 4, lr = lane & 15;
  const int wm = wv >> 2, wn = wv & 3;

  // T1: XCD-aware chunked remap (nwg % 8 == 0 for both grids)
  const int nwg = gridDim.x * gridDim.y;
  const int l = blockIdx.y * gridDim.x + blockIdx.x;
  const int wg = (l & 7) * (nwg >> 3) + (l >> 3);
  const int m0 = (wg / gridDim.x) * 128;
  const int n0 = (wg % gridDim.x) * 256;

  const int NT = K >> 6;

  // stage A half h (64 rows, 1 granule/thread) of k-tile t into slot s
  auto stageA = [&](int s, int t, int h) {
    int row = tid >> 3, g = tid & 7;
    int gsw = g ^ (row & 7);
    gload_lds16(A + (size_t)(m0 + h*64 + row) * K + t*64 + gsw*8,
                (char*)Al[s] + h*8192 + tid*16);
  };
  // stage B half h (128 rows, 2 granules/thread) of k-tile t into slot s
  auto stageB = [&](int s, int t, int h) {
    #pragma unroll
    for (int u = 0; u < 2; ++u) {
      int gi = tid + u*512;
      int row = gi >> 3, g = gi & 7;
      int gsw = g ^ (row & 7);
      gload_lds16(Bt + (size_t)(n0 + h*128 + row) * K + t*64 + gsw*8,
                  (char*)Bl[s] + h*16384 + gi*16);
    }
  };

  f32x4 acc[2][2][2][2];
  #pragma unroll
  for (int i = 0; i < 2; ++i)
    #pragma unroll
    for (int j = 0; j < 2; ++j)
      #pragma unroll
      for (int p = 0; p < 2; ++p)
        #pragma unroll
        for (int q = 0; q < 2; ++q) acc[i][j][p][q] = (f32x4){0.f,0.f,0.f,0.f};

  // prologue: tile0 complete (6 loads) + B0/A0 of tile1 (3 loads) in flight
  stageA(0, 0, 0); stageB(0, 0, 0); stageA(0, 0, 1); stageB(0, 0, 1);
  if (NT > 1) { stageB(1, 1, 0); stageA(1, 1, 0); }
  asm volatile("s_waitcnt vmcnt(3)" ::: "memory");
  __builtin_amdgcn_s_barrier();

#define GPH(MhC, NhC, STAGE, ISPH4, VMOK)  do {                                 \
    short8 af_[2][2], bf_[2][2];                                                \
    _Pragma("unroll") for (int mf = 0; mf < 2; ++mf) {                          \
      int rA = (MhC)*64 + wm*32 + mf*16 + lr;                                   \
      int r7 = rA & 7;                                                          \
      af_[mf][0] = *(const short8*)(Asb + rA*128 + ((lg      ^ r7) << 4));      \
      af_[mf][1] = *(const short8*)(Asb + rA*128 + (((4|lg) ^ r7) << 4));       \
    }                                                                           \
    _Pragma("unroll") for (int nf = 0; nf < 2; ++nf) {                          \
      int rB = (NhC)*128 + wn*32 + nf*16 + lr;                                  \
      int r7 = rB & 7;                                                          \
      bf_[nf][0] = *(const short8*)(Bsb + rB*128 + ((lg      ^ r7) << 4));      \
      bf_[nf][1] = *(const short8*)(Bsb + rB*128 + (((4|lg) ^ r7) << 4));       \
    }                                                                           \
    STAGE;                                                                      \
    __builtin_amdgcn_s_barrier();                                               \
    asm volatile("s_waitcnt lgkmcnt(0)" ::: "memory");                          \
    __builtin_amdgcn_sched_barrier(0);                                          \
    __builtin_amdgcn_s_setprio(1);                                              \
    _Pragma("unroll") for (int mf = 0; mf < 2; ++mf)                            \
      _Pragma("unroll") for (int nf = 0; nf < 2; ++nf) {                        \
        acc[MhC][NhC][mf][nf] = __builtin_amdgcn_mfma_f32_16x16x32_bf16(        \
            af_[mf][0], bf_[nf][0], acc[MhC][NhC][mf][nf], 0, 0, 0);            \
        acc[MhC][NhC][mf][nf] = __builtin_amdgcn_mfma_f32_16x16x32_bf16(        \
            af_[mf][1], bf_[nf][1], acc[MhC][NhC][mf][nf], 0, 0, 0);            \
      }                                                                         \
    __builtin_amdgcn_s_setprio(0);                                              \
    if (ISPH4) {                                                                \
      if (VMOK) asm volatile("s_waitcnt vmcnt(3)" ::: "memory");                \
      else      asm volatile("s_waitcnt vmcnt(0)" ::: "memory");                \
    }                                                                           \
    __builtin_amdgcn_s_barrier();                                               \
  } while (0)

  for (int t = 0; t < NT; ++t) {
    const char* Asb = (const char*)Al[t & 1];
    const char* Bsb = (const char*)Bl[t & 1];
    const int s0 = t & 1, s1 = s0 ^ 1;
    const bool p1 = (t + 1 < NT), p2 = (t + 2 < NT);
    GPH(0, 0, if (p1) stageA(s1, t+1, 1), 0, 0);
    GPH(1, 0, if (p1) stageB(s1, t+1, 1), 0, 0);
    GPH(0, 1, if (p2) stageB(s0, t+2, 0), 0, 0);
    GPH(1, 1, if (p2) stageA(s0, t+2, 0), 1, p2);
  }
#undef GPH

  if (QKV) {
    unsigned short* qb = (unsigned short*)outp;
    const size_t SZ = (size_t)BH_ * T_ * D_;
    #pragma unroll
    for (int Mh = 0; Mh < 2; ++Mh)
      #pragma unroll
      for (int mf = 0; mf < 2; ++mf) {
        int mb = m0 + Mh*64 + wm*32 + mf*16 + lg*4;
        #pragma unroll
        for (int Nh = 0; Nh < 2; ++Nh)
          #pragma unroll
          for (int nf = 0; nf < 2; ++nf) {
            int n = n0 + Nh*128 + wn*32 + nf*16 + lr;
            float bv = bias[n];
            int which = n >> 10, c = n & 1023, h = c >> 6, d = c & 63;
            unsigned short* base = qb + (size_t)which * SZ;
            #pragma unroll
            for (int r = 0; r < 4; ++r) {
              int m = mb + r;
              int bb2 = m >> 11, tt = m & 2047;
              float y = acc[Mh][Nh][mf][nf][r] + bv;
              if (which == 0) y *= QSCALE;
              base[((size_t)(bb2*H_ + h)*T_ + tt)*D_ + d] = f2bf(y);
            }
          }
      }
  } else {
    float* out = (float*)outp;
    #pragma unroll
    for (int Mh = 0; Mh < 2; ++Mh)
      #pragma unroll
      for (int mf = 0; mf < 2; ++mf) {
        int mb = m0 + Mh*64 + wm*32 + mf*16 + lg*4;
        #pragma unroll
        for (int Nh = 0; Nh < 2; ++Nh)
          #pragma unroll
          for (int nf = 0; nf < 2; ++nf) {
            int n = n0 + Nh*128 + wn*32 + nf*16 + lr;
            float bv = bias[n];
            #pragma unroll
            for (int r = 0; r < 4; ++r)
              out[(size_t)(mb + r)*N + n] = acc[Mh][Nh][mf][nf][r] + bv;
          }
      }
  }
}

// ---------------- flash attention, balanced: 8 waves = 2 kv-split groups x 4 waves ----
__global__ __launch_bounds__(512) void k_attn(const unsigned short* __restrict__ Qb,
                                              const unsigned short* __restrict__ Kb,
                                              const unsigned short* __restrict__ Vb,
                                              const int* __restrict__ amask,
                                              unsigned short* __restrict__ Yb) {
  __shared__ __align__(16) char pool[65536];   // [g][buf][K 8KB | V 8KB]; merge reuses

  // T1: XCD-aware chunked remap over the 512-block grid
  const int l = blockIdx.y * 8 + blockIdx.x;
  const int wg = (l & 7) * 64 + (l >> 3);
  const int jb = wg & 7;                        // 0..7
  const int bh = wg >> 3;
  const int bb = bh >> 4, hh = bh & 15;

  const int tid = threadIdx.x;
  const int lane = tid & 63, wv = tid >> 6;
  const int g = wv >> 2, w = wv & 3;
  const int hi = lane >> 5, l31 = lane & 31;
  const int tg = tid & 255;

  const unsigned short* Qh = Qb + (size_t)bh * (T_*D_);
  const unsigned short* Kh = Kb + (size_t)bh * (T_*D_);
  const unsigned short* Vh = Vb + (size_t)bh * (T_*D_);

  char* gbase = pool + g * 32768;
  const int kvp = tg & 31, d0v = (tg >> 5) * 8;

  // issue K global_load_lds + V/mask global loads for kv-tile i into buf b
  auto stage_load = [&](int i, int b, short8& sv0, short8& sv1, int& nm) {
    const int kv0 = ((i << 1) | g) << 6;
    char* base = gbase + b * 16384;
    #pragma unroll
    for (int s = 0; s < 2; ++s) {
      int gi = tg + s * 256;
      int row = gi >> 3, gc = gi & 7;
      gload_lds16(Kh + (size_t)(kv0 + row)*D_ + (gc ^ (row & 7)) * 8, base + gi * 16);
    }
    int kv = kv0 + 2 * kvp;
    sv0 = *reinterpret_cast<const short8*>(Vh + (size_t)kv*D_ + d0v);
    sv1 = *reinterpret_cast<const short8*>(Vh + (size_t)(kv + 1)*D_ + d0v);
    nm = amask[bb*T_ + kv0 + lane];
  };
  // write V^T (bf16-pair packed, swizzled) into buf b
  auto stage_write = [&](int b, short8 sv0, short8 sv1) {
    unsigned int* vt = (unsigned int*)(gbase + b * 16384 + 8192);
    #pragma unroll
    for (int jj = 0; jj < 8; ++jj) {
      int d = d0v + jj;
      unsigned int wd = (unsigned short)sv0[jj] | ((unsigned int)(unsigned short)sv1[jj] << 16);
      vt[d * 32 + (kvp ^ ((d & 7) << 2))] = wd;
    }
  };

  auto phase = [&](int qtile) {
    const int nT = qtile + 1;                  // kv-tiles per group
    const int qbase = qtile << 7;
    const int qw = qbase + w * 32;
    const int q  = qw + l31;

    short8 qf[4];
    #pragma unroll
    for (int dt = 0; dt < 4; ++dt)
      qf[dt] = *reinterpret_cast<const short8*>(Qh + (size_t)q*D_ + dt*16 + hi*8);

    f32x16 o0, o1;
    #pragma unroll
    for (int r = 0; r < 16; ++r) { o0[r] = 0.f; o1[r] = 0.f; }
    float mr = -1e30f, ls = 0.f;

    short8 sv0, sv1; int cm;
    stage_load(0, 0, sv0, sv1, cm);
    stage_write(0, sv0, sv1);
    __syncthreads();

    for (int i = 0; i < nT; ++i) {
      const int b = i & 1;
      const bool pf = (i + 1 < nT);
      short8 nv0, nv1; int nm = 0;
      if (pf) stage_load(i + 1, b ^ 1, nv0, nv1, nm);   // EARLY: issue loads
      const int kv0 = ((i << 1) | g) << 6;

      if (kv0 <= qw + 31) {
        const unsigned short* Klb = (const unsigned short*)(gbase + b * 16384);
        const char* Vtb = gbase + b * 16384 + 8192;

        f32x16 st0, st1;
        #pragma unroll
        for (int r = 0; r < 16; ++r) { st0[r] = 0.f; st1[r] = 0.f; }
        __builtin_amdgcn_s_setprio(1);
        #pragma unroll
        for (int dt = 0; dt < 4; ++dt) {
          int gg = dt * 2 + hi;
          int ra = l31;
          short8 kf0 = *reinterpret_cast<const short8*>(Klb + ra*64 + (gg ^ (ra & 7)) * 8);
          st0 = __builtin_amdgcn_mfma_f32_32x32x16_bf16(kf0, qf[dt], st0, 0, 0, 0);
          int rb = 32 + l31;
          short8 kf1 = *reinterpret_cast<const short8*>(Klb + rb*64 + (gg ^ (rb & 7)) * 8);
          st1 = __builtin_amdgcn_mfma_f32_32x32x16_bf16(kf1, qf[dt], st1, 0, 0, 0);
        }
        __builtin_amdgcn_s_setprio(0);

        if (kv0 + 63 > qw) {
          #pragma unroll
          for (int r = 0; r < 16; ++r) {
            int kvl = (r & 3) + 8 * (r >> 2) + 4 * hi;
            if (kv0 + kvl      > q) st0[r] = -1e30f;
            if (kv0 + 32 + kvl > q) st1[r] = -1e30f;
          }
        }
        unsigned long long mb = __ballot(cm != 0);
        if (mb != ~0ull) {
          #pragma unroll
          for (int r = 0; r < 16; ++r) {
            int kvl = (r & 3) + 8 * (r >> 2) + 4 * hi;
            if (!((mb >> kvl) & 1))        st0[r] = -1e30f;
            if (!((mb >> (kvl + 32)) & 1)) st1[r] = -1e30f;
          }
        }

        // online softmax (exp2 domain), defer-max rescale (T13)
        float mm[8];
        #pragma unroll
        for (int r = 0; r < 8; ++r)
          mm[r] = fmaxf(fmaxf(st0[r], st0[r + 8]), fmaxf(st1[r], st1[r + 8]));
        #pragma unroll
        for (int s = 4; s > 0; s >>= 1)
          #pragma unroll
          for (int r = 0; r < s; ++r) mm[r] = fmaxf(mm[r], mm[r + s]);
        float mo = fmaxf(mm[0], __shfl_xor(mm[0], 32));
        if (!__all(mo <= mr + 8.0f)) {
          float mnew = fmaxf(mr, mo);
          float corr = EXP2(mr - mnew);
          ls *= corr;
          #pragma unroll
          for (int r = 0; r < 16; ++r) { o0[r] *= corr; o1[r] *= corr; }
          mr = mnew;
        }
        float rs = 0.f;
        #pragma unroll
        for (int r = 0; r < 16; ++r) {
          st0[r] = EXP2(st0[r] - mr); rs += st0[r];
          st1[r] = EXP2(st1[r] - mr); rs += st1[r];
        }
        rs += __shfl_xor(rs, 32);
        ls += rs;

        // pack P to bf16 pair-words
        unsigned int pw[2][4][2];
        #pragma unroll
        for (int a = 0; a < 4; ++a) {
          pw[0][a][0] = cvtpk_bf16(st0[4*a],   st0[4*a+1]);
          pw[0][a][1] = cvtpk_bf16(st0[4*a+2], st0[4*a+3]);
          pw[1][a][0] = cvtpk_bf16(st1[4*a],   st1[4*a+1]);
          pw[1][a][1] = cvtpk_bf16(st1[4*a+2], st1[4*a+3]);
        }

        // O^T += V^T x P^T
        #pragma unroll
        for (int kt = 0; kt < 4; ++kt) {
          const int t = kt >> 1, h2 = kt & 1;
          unsigned int send0 = hi ? pw[t][2*h2][0]   : pw[t][2*h2+1][0];
          unsigned int send1 = hi ? pw[t][2*h2][1]   : pw[t][2*h2+1][1];
          unsigned int own0  = hi ? pw[t][2*h2+1][0] : pw[t][2*h2][0];
          unsigned int own1  = hi ? pw[t][2*h2+1][1] : pw[t][2*h2][1];
          unsigned int recv0 = __shfl_xor(send0, 32);
          unsigned int recv1 = __shfl_xor(send1, 32);
          union { unsigned int u[4]; short8 v; } pf2;
          pf2.u[0] = hi ? recv0 : own0;
          pf2.u[1] = hi ? recv1 : own1;
          pf2.u[2] = hi ? own0  : recv0;
          pf2.u[3] = hi ? own1  : recv1;
          int gg = kt * 2 + hi;
          int dA = l31;
          short8 vf0 = *reinterpret_cast<const short8*>(Vtb + dA*128 + ((gg ^ (dA & 7)) * 16));
          int dB = 32 + l31;
          short8 vf1 = *reinterpret_cast<const short8*>(Vtb + dB*128 + ((gg ^ (dB & 7)) * 16));
          __builtin_amdgcn_s_setprio(1);
          o0 = __builtin_amdgcn_mfma_f32_32x32x16_bf16(vf0, pf2.v, o0, 0, 0, 0);
          o1 = __builtin_amdgcn_mfma_f32_32x32x16_bf16(vf1, pf2.v, o1, 0, 0, 0);
          __builtin_amdgcn_s_setprio(0);
        }
      }
      if (pf) { stage_write(b ^ 1, nv0, nv1); cm = nm; }   // LATE: V writes
      __syncthreads();
    }

    // ---- merge the two kv-split groups via LDS ----
    float* mbuf = (float*)pool;
    const int idx = w * 64 + lane;
    if (g == 1) {
      #pragma unroll
      for (int r = 0; r < 16; ++r) {
        mbuf[idx + r * 256]        = o0[r];
        mbuf[idx + (16 + r) * 256] = o1[r];
      }
      mbuf[idx + 32 * 256] = mr;
      mbuf[idx + 33 * 256] = ls;
    }
    __syncthreads();
    if (g == 0) {
      float m1 = mbuf[idx + 32 * 256], l1 = mbuf[idx + 33 * 256];
      float m = fmaxf(mr, m1);
      float c0 = EXP2(mr - m), c1 = EXP2(m1 - m);
      float inv = 1.0f / (ls * c0 + l1 * c1);
      size_t rowbase = ((size_t)bb*T_ + q)*C_ + hh*D_;
      #pragma unroll
      for (int a = 0; a < 4; ++a) {
        union { unsigned short h[4]; unsigned long long ll; } y0, y1;
        #pragma unroll
        for (int bq = 0; bq < 4; ++bq) {
          int r = 4*a + bq;
          y0.h[bq] = f2bf((o0[r] * c0 + mbuf[idx + r * 256]        * c1) * inv);
          y1.h[bq] = f2bf((o1[r] * c0 + mbuf[idx + (16 + r) * 256] * c1) * inv);
        }
        int d0o = 8*a + 4*hi;
        *reinterpret_cast<unsigned long long*>(Yb + rowbase + d0o)      = y0.ll;
        *reinterpret_cast<unsigned long long*>(Yb + rowbase + 32 + d0o) = y1.ll;
      }
    }
    __syncthreads();
  };

  phase(15 - jb);
  phase(jb);
}

extern "C" void kernel_launch(void* const* d_in, const int* in_sizes, int n_in,
                              void* d_out, int out_size, void* d_ws, size_t ws_size,
                              hipStream_t stream) {
  const float* x      = (const float*)d_in[0];
  const float* W_attn = (const float*)d_in[1];
  const float* b_attn = (const float*)d_in[2];
  const float* W_proj = (const float*)d_in[3];
  const float* b_proj = (const float*)d_in[4];
  const int*   amask  = (const int*)d_in[5];
  float* out = (float*)d_out;

  char* ws = (char*)d_ws;
  size_t off = 0;
  auto alloc = [&](size_t bytes) { char* p = ws + off; off += (bytes + 255) & ~(size_t)255; return p; };
  unsigned short* xb   = (unsigned short*)alloc((size_t)M_ * C_ * 2);
  unsigned short* Wta  = (unsigned short*)alloc((size_t)3 * C_ * C_ * 2);
  unsigned short* Wtp  = (unsigned short*)alloc((size_t)C_ * C_ * 2);
  unsigned short* qkvb = (unsigned short*)alloc((size_t)3 * BH_ * T_ * D_ * 2);
  unsigned short* Yb   = (unsigned short*)alloc((size_t)M_ * C_ * 2);

  k_cvt<<<(M_ * C_) / 1024, 256, 0, stream>>>(x, xb, M_ * C_);
  k_tr<<<dim3(3*C_/32, C_/32), dim3(32, 8), 0, stream>>>(W_attn, Wta, C_, 3*C_);
  k_tr<<<dim3(C_/32,  C_/32),  dim3(32, 8), 0, stream>>>(W_proj, Wtp, C_, C_);

  k_gemm8<1><<<dim3(3*C_/256, M_/128), 512, 0, stream>>>(xb, Wta, b_attn, qkvb, 3*C_, C_);

  unsigned short* Qb = qkvb;
  unsigned short* Kb = qkvb + (size_t)BH_ * T_ * D_;
  unsigned short* Vb = qkvb + 2 * (size_t)BH_ * T_ * D_;
  k_attn<<<dim3(8, BH_), 512, 0, stream>>>(Qb, Kb, Vb, amask, Yb);

  k_gemm8<0><<<dim3(C_/256, M_/128), 512, 0, stream>>>(Yb, Wtp, b_proj, out, C_, C_);
}

// Round 8
// 187.514 us; speedup vs baseline: 2.4414x; 1.0329x over previous
//
#include <hip/hip_runtime.h>
#include <hip/hip_bf16.h>
#include <stdint.h>

#define B_ 4
#define T_ 2048
#define C_ 1024
#define H_ 16
#define D_ 64
#define BH_ (B_*H_)
#define M_ (B_*T_)   // 8192 rows

typedef __attribute__((ext_vector_type(8))) short short8;
typedef __attribute__((ext_vector_type(4))) float f32x4;
typedef __attribute__((ext_vector_type(16))) float f32x16;

#if __has_builtin(__builtin_amdgcn_exp2f)
#define EXP2(x) __builtin_amdgcn_exp2f(x)
#else
#define EXP2(x) exp2f(x)
#endif

// 1/sqrt(D) * log2(e), folded into Q at QKV-GEMM epilogue
#define QSCALE 0.18033688011112043f

__device__ __forceinline__ unsigned short f2bf(float f) {
  union { float f; unsigned int u; } v; v.f = f;
  unsigned int r = v.u + 0x7FFFu + ((v.u >> 16) & 1u);   // RNE
  return (unsigned short)(r >> 16);
}

__device__ __forceinline__ unsigned int cvtpk_bf16(float lo, float hi) {
  unsigned int r;
  asm("v_cvt_pk_bf16_f32 %0, %1, %2" : "=v"(r) : "v"(lo), "v"(hi));
  return r;
}

__device__ __forceinline__ void gload_lds16(const void* g, void* l) {
  __builtin_amdgcn_global_load_lds(
      (__attribute__((address_space(1))) void*)g,
      (__attribute__((address_space(3))) void*)l, 16, 0, 0);
}

// ---------------- fp32 -> bf16 convert (vectorized) ----------------
__global__ __launch_bounds__(256) void k_cvt(const float* __restrict__ in,
                                             unsigned short* __restrict__ out, int n) {
  int i = (blockIdx.x * 256 + threadIdx.x) * 4;
  if (i >= n) return;
  float4 v = *reinterpret_cast<const float4*>(in + i);
  union { unsigned short u[4]; unsigned long long ll; } o;
  o.u[0] = f2bf(v.x); o.u[1] = f2bf(v.y); o.u[2] = f2bf(v.z); o.u[3] = f2bf(v.w);
  *reinterpret_cast<unsigned long long*>(out + i) = o.ll;
}

// ---------------- transpose+convert W [K][N] f32 -> Wt [N][K] bf16 ----------------
__global__ __launch_bounds__(256) void k_tr(const float* __restrict__ W,
                                            unsigned short* __restrict__ Wt, int K, int N) {
  __shared__ float t[32][33];
  int n0 = blockIdx.x * 32, k0 = blockIdx.y * 32;
  int tx = threadIdx.x, ty = threadIdx.y;    // (32,8)
  #pragma unroll
  for (int j = 0; j < 4; j++)
    t[ty + j*8][tx] = W[(size_t)(k0 + ty + j*8) * N + n0 + tx];
  __syncthreads();
  #pragma unroll
  for (int j = 0; j < 4; j++)
    Wt[(size_t)(n0 + ty + j*8) * K + k0 + tx] = f2bf(t[tx][ty + j*8]);
}

// ---------------- GEMM, 8-phase counted-vmcnt (T2+T3+T4+T5), BM=128 BN=256 BK=64 ----
template<int QKV>
__global__ __launch_bounds__(512) void k_gemm8(const unsigned short* __restrict__ A,
                                               const unsigned short* __restrict__ Bt,
                                               const float* __restrict__ bias,
                                               void* __restrict__ outp, int N, int K) {
  __shared__ __align__(16) unsigned short Al[2][128*64];   // 32 KB
  __shared__ __align__(16) unsigned short Bl[2][256*64];   // 64 KB

  const int tid = threadIdx.x;
  const int lane = tid & 63, wv = tid >> 6;
  const int lg = lane >> 4, lr = lane & 15;
  const int wm = wv >> 2, wn = wv & 3;

  // T1: XCD-aware chunked remap (nwg % 8 == 0 for both grids)
  const int nwg = gridDim.x * gridDim.y;
  const int l = blockIdx.y * gridDim.x + blockIdx.x;
  const int wg = (l & 7) * (nwg >> 3) + (l >> 3);
  const int m0 = (wg / gridDim.x) * 128;
  const int n0 = (wg % gridDim.x) * 256;

  const int NT = K >> 6;

  auto stageA = [&](int s, int t, int h) {
    int row = tid >> 3, g = tid & 7;
    int gsw = g ^ (row & 7);
    gload_lds16(A + (size_t)(m0 + h*64 + row) * K + t*64 + gsw*8,
                (char*)Al[s] + h*8192 + tid*16);
  };
  auto stageB = [&](int s, int t, int h) {
    #pragma unroll
    for (int u = 0; u < 2; ++u) {
      int gi = tid + u*512;
      int row = gi >> 3, g = gi & 7;
      int gsw = g ^ (row & 7);
      gload_lds16(Bt + (size_t)(n0 + h*128 + row) * K + t*64 + gsw*8,
                  (char*)Bl[s] + h*16384 + gi*16);
    }
  };

  f32x4 acc[2][2][2][2];
  #pragma unroll
  for (int i = 0; i < 2; ++i)
    #pragma unroll
    for (int j = 0; j < 2; ++j)
      #pragma unroll
      for (int p = 0; p < 2; ++p)
        #pragma unroll
        for (int q = 0; q < 2; ++q) acc[i][j][p][q] = (f32x4){0.f,0.f,0.f,0.f};

  stageA(0, 0, 0); stageB(0, 0, 0); stageA(0, 0, 1); stageB(0, 0, 1);
  if (NT > 1) { stageB(1, 1, 0); stageA(1, 1, 0); }
  asm volatile("s_waitcnt vmcnt(3)" ::: "memory");
  __builtin_amdgcn_s_barrier();

#define GPH(MhC, NhC, STAGE, ISPH4, VMOK)  do {                                 \
    short8 af_[2][2], bf_[2][2];                                                \
    _Pragma("unroll") for (int mf = 0; mf < 2; ++mf) {                          \
      int rA = (MhC)*64 + wm*32 + mf*16 + lr;                                   \
      int r7 = rA & 7;                                                          \
      af_[mf][0] = *(const short8*)(Asb + rA*128 + ((lg      ^ r7) << 4));      \
      af_[mf][1] = *(const short8*)(Asb + rA*128 + (((4|lg) ^ r7) << 4));       \
    }                                                                           \
    _Pragma("unroll") for (int nf = 0; nf < 2; ++nf) {                          \
      int rB = (NhC)*128 + wn*32 + nf*16 + lr;                                  \
      int r7 = rB & 7;                                                          \
      bf_[nf][0] = *(const short8*)(Bsb + rB*128 + ((lg      ^ r7) << 4));      \
      bf_[nf][1] = *(const short8*)(Bsb + rB*128 + (((4|lg) ^ r7) << 4));       \
    }                                                                           \
    STAGE;                                                                      \
    __builtin_amdgcn_s_barrier();                                               \
    asm volatile("s_waitcnt lgkmcnt(0)" ::: "memory");                          \
    __builtin_amdgcn_sched_barrier(0);                                          \
    __builtin_amdgcn_s_setprio(1);                                              \
    _Pragma("unroll") for (int mf = 0; mf < 2; ++mf)                            \
      _Pragma("unroll") for (int nf = 0; nf < 2; ++nf) {                        \
        acc[MhC][NhC][mf][nf] = __builtin_amdgcn_mfma_f32_16x16x32_bf16(        \
            af_[mf][0], bf_[nf][0], acc[MhC][NhC][mf][nf], 0, 0, 0);            \
        acc[MhC][NhC][mf][nf] = __builtin_amdgcn_mfma_f32_16x16x32_bf16(        \
            af_[mf][1], bf_[nf][1], acc[MhC][NhC][mf][nf], 0, 0, 0);            \
      }                                                                         \
    __builtin_amdgcn_s_setprio(0);                                              \
    if (ISPH4) {                                                                \
      if (VMOK) asm volatile("s_waitcnt vmcnt(3)" ::: "memory");                \
      else      asm volatile("s_waitcnt vmcnt(0)" ::: "memory");                \
    }                                                                           \
    __builtin_amdgcn_s_barrier();                                               \
  } while (0)

  for (int t = 0; t < NT; ++t) {
    const char* Asb = (const char*)Al[t & 1];
    const char* Bsb = (const char*)Bl[t & 1];
    const int s0 = t & 1, s1 = s0 ^ 1;
    const bool p1 = (t + 1 < NT), p2 = (t + 2 < NT);
    GPH(0, 0, if (p1) stageA(s1, t+1, 1), 0, 0);
    GPH(1, 0, if (p1) stageB(s1, t+1, 1), 0, 0);
    GPH(0, 1, if (p2) stageB(s0, t+2, 0), 0, 0);
    GPH(1, 1, if (p2) stageA(s0, t+2, 0), 1, p2);
  }
#undef GPH

  if (QKV) {
    unsigned short* qb = (unsigned short*)outp;
    const size_t SZ = (size_t)BH_ * T_ * D_;
    #pragma unroll
    for (int Mh = 0; Mh < 2; ++Mh)
      #pragma unroll
      for (int mf = 0; mf < 2; ++mf) {
        int mb = m0 + Mh*64 + wm*32 + mf*16 + lg*4;
        #pragma unroll
        for (int Nh = 0; Nh < 2; ++Nh)
          #pragma unroll
          for (int nf = 0; nf < 2; ++nf) {
            int n = n0 + Nh*128 + wn*32 + nf*16 + lr;
            float bv = bias[n];
            int which = n >> 10, c = n & 1023, h = c >> 6, d = c & 63;
            unsigned short* base = qb + (size_t)which * SZ;
            #pragma unroll
            for (int r = 0; r < 4; ++r) {
              int m = mb + r;
              int bb2 = m >> 11, tt = m & 2047;
              float y = acc[Mh][Nh][mf][nf][r] + bv;
              if (which == 0) y *= QSCALE;
              base[((size_t)(bb2*H_ + h)*T_ + tt)*D_ + d] = f2bf(y);
            }
          }
      }
  } else {
    float* out = (float*)outp;
    #pragma unroll
    for (int Mh = 0; Mh < 2; ++Mh)
      #pragma unroll
      for (int mf = 0; mf < 2; ++mf) {
        int mb = m0 + Mh*64 + wm*32 + mf*16 + lg*4;
        #pragma unroll
        for (int Nh = 0; Nh < 2; ++Nh)
          #pragma unroll
          for (int nf = 0; nf < 2; ++nf) {
            int n = n0 + Nh*128 + wn*32 + nf*16 + lr;
            float bv = bias[n];
            #pragma unroll
            for (int r = 0; r < 4; ++r)
              out[(size_t)(mb + r)*N + n] = acc[Mh][Nh][mf][nf][r] + bv;
          }
      }
  }
}

// ---------------- flash attention, 4-wave blocks, one 128-row q-tile each ----------
// Grid 16x64 = 1024 blocks; remap: XCD chunk = 8 bh, tiles descending (heavy first).
// No kv group-split, no merge: more independent blocks per CU for latency hiding.
// S^T = mfma(K, Q): lane owns q; softmax in-register (exp2 domain, Q pre-scaled).
// T14 stage split, T5 setprio, T13 defer-max — verified round-7 compute body.
__global__ __launch_bounds__(256, 2) void k_attn4(const unsigned short* __restrict__ Qb,
                                                  const unsigned short* __restrict__ Kb,
                                                  const unsigned short* __restrict__ Vb,
                                                  const int* __restrict__ amask,
                                                  unsigned short* __restrict__ Yb) {
  __shared__ __align__(16) char pool[32768];   // [buf][K 8KB | V 8KB]

  // remap: l&7 -> XCD; within XCD: tile 15 of 8 bh, then tile 14, ... (heavy first)
  const int l = blockIdx.y * 16 + blockIdx.x;
  const int local = l >> 3;                     // 0..127
  const int tq = 15 - (local >> 3);             // q-tile index
  const int bh = (l & 7) * 8 + (local & 7);
  const int bb = bh >> 4, hh = bh & 15;

  const int tid = threadIdx.x;
  const int lane = tid & 63, w = tid >> 6;
  const int hi = lane >> 5, l31 = lane & 31;

  const unsigned short* Qh = Qb + (size_t)bh * (T_*D_);
  const unsigned short* Kh = Kb + (size_t)bh * (T_*D_);
  const unsigned short* Vh = Vb + (size_t)bh * (T_*D_);

  const int kvp = tid & 31, d0v = (tid >> 5) * 8;

  auto stage_load = [&](int i, int b, short8& sv0, short8& sv1, int& nm) {
    const int kv0 = i << 6;
    char* base = pool + b * 16384;
    #pragma unroll
    for (int s = 0; s < 2; ++s) {
      int gi = tid + s * 256;
      int row = gi >> 3, gc = gi & 7;
      gload_lds16(Kh + (size_t)(kv0 + row)*D_ + (gc ^ (row & 7)) * 8, base + gi * 16);
    }
    int kv = kv0 + 2 * kvp;
    sv0 = *reinterpret_cast<const short8*>(Vh + (size_t)kv*D_ + d0v);
    sv1 = *reinterpret_cast<const short8*>(Vh + (size_t)(kv + 1)*D_ + d0v);
    nm = amask[bb*T_ + kv0 + lane];
  };
  auto stage_write = [&](int b, short8 sv0, short8 sv1) {
    unsigned int* vt = (unsigned int*)(pool + b * 16384 + 8192);
    #pragma unroll
    for (int jj = 0; jj < 8; ++jj) {
      int d = d0v + jj;
      unsigned int wd = (unsigned short)sv0[jj] | ((unsigned int)(unsigned short)sv1[jj] << 16);
      vt[d * 32 + (kvp ^ ((d & 7) << 2))] = wd;
    }
  };

  const int nT = 2 * tq + 2;                   // kv-tiles for this q-tile
  const int qbase = tq << 7;
  const int qw = qbase + w * 32;
  const int q  = qw + l31;

  short8 qf[4];
  #pragma unroll
  for (int dt = 0; dt < 4; ++dt)
    qf[dt] = *reinterpret_cast<const short8*>(Qh + (size_t)q*D_ + dt*16 + hi*8);

  f32x16 o0, o1;
  #pragma unroll
  for (int r = 0; r < 16; ++r) { o0[r] = 0.f; o1[r] = 0.f; }
  float mr = -1e30f, ls = 0.f;

  short8 sv0, sv1; int cm;
  stage_load(0, 0, sv0, sv1, cm);
  stage_write(0, sv0, sv1);
  __syncthreads();

  for (int i = 0; i < nT; ++i) {
    const int b = i & 1;
    const bool pf = (i + 1 < nT);
    short8 nv0, nv1; int nm = 0;
    if (pf) stage_load(i + 1, b ^ 1, nv0, nv1, nm);   // EARLY: issue loads
    const int kv0 = i << 6;

    if (kv0 <= qw + 31) {
      const unsigned short* Klb = (const unsigned short*)(pool + b * 16384);
      const char* Vtb = pool + b * 16384 + 8192;

      f32x16 st0, st1;
      #pragma unroll
      for (int r = 0; r < 16; ++r) { st0[r] = 0.f; st1[r] = 0.f; }
      __builtin_amdgcn_s_setprio(1);
      #pragma unroll
      for (int dt = 0; dt < 4; ++dt) {
        int gg = dt * 2 + hi;
        int ra = l31;
        short8 kf0 = *reinterpret_cast<const short8*>(Klb + ra*64 + (gg ^ (ra & 7)) * 8);
        st0 = __builtin_amdgcn_mfma_f32_32x32x16_bf16(kf0, qf[dt], st0, 0, 0, 0);
        int rb = 32 + l31;
        short8 kf1 = *reinterpret_cast<const short8*>(Klb + rb*64 + (gg ^ (rb & 7)) * 8);
        st1 = __builtin_amdgcn_mfma_f32_32x32x16_bf16(kf1, qf[dt], st1, 0, 0, 0);
      }
      __builtin_amdgcn_s_setprio(0);

      if (kv0 + 63 > qw) {
        #pragma unroll
        for (int r = 0; r < 16; ++r) {
          int kvl = (r & 3) + 8 * (r >> 2) + 4 * hi;
          if (kv0 + kvl      > q) st0[r] = -1e30f;
          if (kv0 + 32 + kvl > q) st1[r] = -1e30f;
        }
      }
      unsigned long long mb = __ballot(cm != 0);
      if (mb != ~0ull) {
        #pragma unroll
        for (int r = 0; r < 16; ++r) {
          int kvl = (r & 3) + 8 * (r >> 2) + 4 * hi;
          if (!((mb >> kvl) & 1))        st0[r] = -1e30f;
          if (!((mb >> (kvl + 32)) & 1)) st1[r] = -1e30f;
        }
      }

      // online softmax (exp2 domain), defer-max rescale (T13)
      float mm[8];
      #pragma unroll
      for (int r = 0; r < 8; ++r)
        mm[r] = fmaxf(fmaxf(st0[r], st0[r + 8]), fmaxf(st1[r], st1[r + 8]));
      #pragma unroll
      for (int s = 4; s > 0; s >>= 1)
        #pragma unroll
        for (int r = 0; r < s; ++r) mm[r] = fmaxf(mm[r], mm[r + s]);
      float mo = fmaxf(mm[0], __shfl_xor(mm[0], 32));
      if (!__all(mo <= mr + 8.0f)) {
        float mnew = fmaxf(mr, mo);
        float corr = EXP2(mr - mnew);
        ls *= corr;
        #pragma unroll
        for (int r = 0; r < 16; ++r) { o0[r] *= corr; o1[r] *= corr; }
        mr = mnew;
      }
      float rs = 0.f;
      #pragma unroll
      for (int r = 0; r < 16; ++r) {
        st0[r] = EXP2(st0[r] - mr); rs += st0[r];
        st1[r] = EXP2(st1[r] - mr); rs += st1[r];
      }
      rs += __shfl_xor(rs, 32);
      ls += rs;

      // pack P to bf16 pair-words
      unsigned int pw[2][4][2];
      #pragma unroll
      for (int a = 0; a < 4; ++a) {
        pw[0][a][0] = cvtpk_bf16(st0[4*a],   st0[4*a+1]);
        pw[0][a][1] = cvtpk_bf16(st0[4*a+2], st0[4*a+3]);
        pw[1][a][0] = cvtpk_bf16(st1[4*a],   st1[4*a+1]);
        pw[1][a][1] = cvtpk_bf16(st1[4*a+2], st1[4*a+3]);
      }

      // O^T += V^T x P^T
      #pragma unroll
      for (int kt = 0; kt < 4; ++kt) {
        const int t = kt >> 1, h2 = kt & 1;
        unsigned int send0 = hi ? pw[t][2*h2][0]   : pw[t][2*h2+1][0];
        unsigned int send1 = hi ? pw[t][2*h2][1]   : pw[t][2*h2+1][1];
        unsigned int own0  = hi ? pw[t][2*h2+1][0] : pw[t][2*h2][0];
        unsigned int own1  = hi ? pw[t][2*h2+1][1] : pw[t][2*h2][1];
        unsigned int recv0 = __shfl_xor(send0, 32);
        unsigned int recv1 = __shfl_xor(send1, 32);
        union { unsigned int u[4]; short8 v; } pf2;
        pf2.u[0] = hi ? recv0 : own0;
        pf2.u[1] = hi ? recv1 : own1;
        pf2.u[2] = hi ? own0  : recv0;
        pf2.u[3] = hi ? own1  : recv1;
        int gg = kt * 2 + hi;
        int dA = l31;
        short8 vf0 = *reinterpret_cast<const short8*>(Vtb + dA*128 + ((gg ^ (dA & 7)) * 16));
        int dB = 32 + l31;
        short8 vf1 = *reinterpret_cast<const short8*>(Vtb + dB*128 + ((gg ^ (dB & 7)) * 16));
        __builtin_amdgcn_s_setprio(1);
        o0 = __builtin_amdgcn_mfma_f32_32x32x16_bf16(vf0, pf2.v, o0, 0, 0, 0);
        o1 = __builtin_amdgcn_mfma_f32_32x32x16_bf16(vf1, pf2.v, o1, 0, 0, 0);
        __builtin_amdgcn_s_setprio(0);
      }
    }
    if (pf) { stage_write(b ^ 1, nv0, nv1); cm = nm; }   // LATE: V writes
    __syncthreads();
  }

  // ---- epilogue: direct write (no merge) ----
  float inv = 1.0f / ls;
  size_t rowbase = ((size_t)bb*T_ + q)*C_ + hh*D_;
  #pragma unroll
  for (int a = 0; a < 4; ++a) {
    union { unsigned short h[4]; unsigned long long ll; } y0, y1;
    #pragma unroll
    for (int bq = 0; bq < 4; ++bq) {
      int r = 4*a + bq;
      y0.h[bq] = f2bf(o0[r] * inv);
      y1.h[bq] = f2bf(o1[r] * inv);
    }
    int d0o = 8*a + 4*hi;
    *reinterpret_cast<unsigned long long*>(Yb + rowbase + d0o)      = y0.ll;
    *reinterpret_cast<unsigned long long*>(Yb + rowbase + 32 + d0o) = y1.ll;
  }
}

extern "C" void kernel_launch(void* const* d_in, const int* in_sizes, int n_in,
                              void* d_out, int out_size, void* d_ws, size_t ws_size,
                              hipStream_t stream) {
  const float* x      = (const float*)d_in[0];
  const float* W_attn = (const float*)d_in[1];
  const float* b_attn = (const float*)d_in[2];
  const float* W_proj = (const float*)d_in[3];
  const float* b_proj = (const float*)d_in[4];
  const int*   amask  = (const int*)d_in[5];
  float* out = (float*)d_out;

  char* ws = (char*)d_ws;
  size_t off = 0;
  auto alloc = [&](size_t bytes) { char* p = ws + off; off += (bytes + 255) & ~(size_t)255; return p; };
  unsigned short* xb   = (unsigned short*)alloc((size_t)M_ * C_ * 2);
  unsigned short* Wta  = (unsigned short*)alloc((size_t)3 * C_ * C_ * 2);
  unsigned short* Wtp  = (unsigned short*)alloc((size_t)C_ * C_ * 2);
  unsigned short* qkvb = (unsigned short*)alloc((size_t)3 * BH_ * T_ * D_ * 2);
  unsigned short* Yb   = (unsigned short*)alloc((size_t)M_ * C_ * 2);

  k_cvt<<<(M_ * C_) / 1024, 256, 0, stream>>>(x, xb, M_ * C_);
  k_tr<<<dim3(3*C_/32, C_/32), dim3(32, 8), 0, stream>>>(W_attn, Wta, C_, 3*C_);
  k_tr<<<dim3(C_/32,  C_/32),  dim3(32, 8), 0, stream>>>(W_proj, Wtp, C_, C_);

  k_gemm8<1><<<dim3(3*C_/256, M_/128), 512, 0, stream>>>(xb, Wta, b_attn, qkvb, 3*C_, C_);

  unsigned short* Qb = qkvb;
  unsigned short* Kb = qkvb + (size_t)BH_ * T_ * D_;
  unsigned short* Vb = qkvb + 2 * (size_t)BH_ * T_ * D_;
  k_attn4<<<dim3(16, BH_/1), 256, 0, stream>>>(Qb, Kb, Vb, amask, Yb);

  k_gemm8<0><<<dim3(C_/256, M_/128), 512, 0, stream>>>(Yb, Wtp, b_proj, out, C_, C_);
}

// Round 9
// 175.763 us; speedup vs baseline: 2.6047x; 1.0669x over previous
//
#include <hip/hip_runtime.h>
#include <hip/hip_bf16.h>
#include <stdint.h>

#define B_ 4
#define T_ 2048
#define C_ 1024
#define H_ 16
#define D_ 64
#define BH_ (B_*H_)
#define M_ (B_*T_)   // 8192 rows

typedef __attribute__((ext_vector_type(8))) short short8;
typedef __attribute__((ext_vector_type(4))) float f32x4;
typedef __attribute__((ext_vector_type(16))) float f32x16;

#if __has_builtin(__builtin_amdgcn_exp2f)
#define EXP2(x) __builtin_amdgcn_exp2f(x)
#else
#define EXP2(x) exp2f(x)
#endif

// 1/sqrt(D) * log2(e), folded into Q at QKV-GEMM epilogue
#define QSCALE 0.18033688011112043f

__device__ __forceinline__ unsigned short f2bf(float f) {
  union { float f; unsigned int u; } v; v.f = f;
  unsigned int r = v.u + 0x7FFFu + ((v.u >> 16) & 1u);   // RNE
  return (unsigned short)(r >> 16);
}

__device__ __forceinline__ unsigned int cvtpk_bf16(float lo, float hi) {
  unsigned int r;
  asm("v_cvt_pk_bf16_f32 %0, %1, %2" : "=v"(r) : "v"(lo), "v"(hi));
  return r;
}

__device__ __forceinline__ void gload_lds16(const void* g, void* l) {
  __builtin_amdgcn_global_load_lds(
      (__attribute__((address_space(1))) void*)g,
      (__attribute__((address_space(3))) void*)l, 16, 0, 0);
}

// ---------------- fp32 -> bf16 convert (vectorized) ----------------
__global__ __launch_bounds__(256) void k_cvt(const float* __restrict__ in,
                                             unsigned short* __restrict__ out, int n) {
  int i = (blockIdx.x * 256 + threadIdx.x) * 4;
  if (i >= n) return;
  float4 v = *reinterpret_cast<const float4*>(in + i);
  union { unsigned short u[4]; unsigned long long ll; } o;
  o.u[0] = f2bf(v.x); o.u[1] = f2bf(v.y); o.u[2] = f2bf(v.z); o.u[3] = f2bf(v.w);
  *reinterpret_cast<unsigned long long*>(out + i) = o.ll;
}

// ---------------- transpose+convert W [K][N] f32 -> Wt [N][K] bf16 ----------------
__global__ __launch_bounds__(256) void k_tr(const float* __restrict__ W,
                                            unsigned short* __restrict__ Wt, int K, int N) {
  __shared__ float t[32][33];
  int n0 = blockIdx.x * 32, k0 = blockIdx.y * 32;
  int tx = threadIdx.x, ty = threadIdx.y;    // (32,8)
  #pragma unroll
  for (int j = 0; j < 4; j++)
    t[ty + j*8][tx] = W[(size_t)(k0 + ty + j*8) * N + n0 + tx];
  __syncthreads();
  #pragma unroll
  for (int j = 0; j < 4; j++)
    Wt[(size_t)(n0 + ty + j*8) * K + k0 + tx] = f2bf(t[tx][ty + j*8]);
}

// ---------------- GEMM v2: BM=256 BN=128 BK=64, 2 phases x 16 MFMA per K-tile -------
// 8 waves = 2M x 4N; per-wave output 128x32 (acc[8][2] f32x4).
// LDS: dbuf A[256][64] (64KB) + B[128][64] (32KB), XOR-swizzled 16B granules.
// B-fragments read once per K-tile, held across both phases.
// Counted vmcnt: P0 stages {B0,B1,A0,A2} of t+1, end vmcnt(4); P1 stages {A1,A3},
// end vmcnt(2). Never 0 mid-loop.
template<int QKV>
__global__ __launch_bounds__(512) void k_gemm8(const unsigned short* __restrict__ A,
                                               const unsigned short* __restrict__ Bt,
                                               const float* __restrict__ bias,
                                               void* __restrict__ outp, int N, int K) {
  __shared__ __align__(16) unsigned short Al[2][256*64];   // 64 KB
  __shared__ __align__(16) unsigned short Bl[2][128*64];   // 32 KB

  const int tid = threadIdx.x;
  const int lane = tid & 63, wv = tid >> 6;
  const int lg = lane >> 4, lr = lane & 15;
  const int wm = wv >> 2, wn = wv & 3;     // 2M x 4N

  // T1: XCD-aware chunked remap (nwg % 8 == 0 for both grids)
  const int nwg = gridDim.x * gridDim.y;
  const int l = blockIdx.y * gridDim.x + blockIdx.x;
  const int wg = (l & 7) * (nwg >> 3) + (l >> 3);
  const int m0 = (wg / gridDim.x) * 256;
  const int n0 = (wg % gridDim.x) * 128;

  const int NT = K >> 6;

  // stage unit = 64 rows x 64 k (8 KB), 1 instr/thread, pre-swizzled global source
  auto stageA = [&](int s, int t, int u) {
    int row = u*64 + (tid >> 3), g = tid & 7;
    gload_lds16(A + (size_t)(m0 + row) * K + t*64 + (g ^ (row & 7)) * 8,
                (char*)Al + s*32768 + u*8192 + tid*16);
  };
  auto stageB = [&](int s, int t, int u) {
    int row = u*64 + (tid >> 3), g = tid & 7;
    gload_lds16(Bt + (size_t)(n0 + row) * K + t*64 + (g ^ (row & 7)) * 8,
                (char*)Bl + s*16384 + u*8192 + tid*16);
  };

  f32x4 acc[8][2];
  #pragma unroll
  for (int i = 0; i < 8; ++i)
    #pragma unroll
    for (int j = 0; j < 2; ++j) acc[i][j] = (f32x4){0.f, 0.f, 0.f, 0.f};

  // prologue: tile0 fully staged, A1/A3 issued last
  stageB(0,0,0); stageB(0,0,1); stageA(0,0,0); stageA(0,0,2);
  stageA(0,0,1); stageA(0,0,3);
  asm volatile("s_waitcnt vmcnt(2)" ::: "memory");
  __builtin_amdgcn_s_barrier();

#define GPH(MhC, READB, STAGE, WAITE)  do {                                     \
    short8 af_[4][2];                                                           \
    _Pragma("unroll") for (int mf = 0; mf < 4; ++mf) {                          \
      int rA = wm*128 + (MhC)*64 + mf*16 + lr;                                  \
      int r7 = rA & 7;                                                          \
      af_[mf][0] = *(const short8*)(Asb + rA*128 + ((lg      ^ r7) << 4));      \
      af_[mf][1] = *(const short8*)(Asb + rA*128 + (((4|lg) ^ r7) << 4));       \
    }                                                                           \
    if (READB) {                                                                \
      _Pragma("unroll") for (int nf = 0; nf < 2; ++nf) {                        \
        int rB = wn*32 + nf*16 + lr;                                            \
        int r7 = rB & 7;                                                        \
        bf_[nf][0] = *(const short8*)(Bsb + rB*128 + ((lg      ^ r7) << 4));    \
        bf_[nf][1] = *(const short8*)(Bsb + rB*128 + (((4|lg) ^ r7) << 4));     \
      }                                                                         \
    }                                                                           \
    STAGE;                                                                      \
    __builtin_amdgcn_s_barrier();                                               \
    asm volatile("s_waitcnt lgkmcnt(0)" ::: "memory");                          \
    __builtin_amdgcn_sched_barrier(0);                                          \
    __builtin_amdgcn_s_setprio(1);                                              \
    _Pragma("unroll") for (int kh = 0; kh < 2; ++kh)                            \
      _Pragma("unroll") for (int mf = 0; mf < 4; ++mf)                          \
        _Pragma("unroll") for (int nf = 0; nf < 2; ++nf)                        \
          acc[(MhC)*4+mf][nf] = __builtin_amdgcn_mfma_f32_16x16x32_bf16(        \
              af_[mf][kh], bf_[nf][kh], acc[(MhC)*4+mf][nf], 0, 0, 0);          \
    __builtin_amdgcn_s_setprio(0);                                              \
    WAITE;                                                                      \
    __builtin_amdgcn_s_barrier();                                               \
  } while (0)

  for (int t = 0; t < NT; ++t) {
    const char* Asb = (const char*)Al + (t & 1) * 32768;
    const char* Bsb = (const char*)Bl + (t & 1) * 16384;
    const int s1 = (t & 1) ^ 1;
    const bool p1 = (t + 1 < NT);
    short8 bf_[2][2];
    GPH(0, 1,
        if (p1) { stageB(s1,t+1,0); stageB(s1,t+1,1); stageA(s1,t+1,0); stageA(s1,t+1,2); },
        if (p1) { asm volatile("s_waitcnt vmcnt(4)" ::: "memory"); }
        else    { asm volatile("s_waitcnt vmcnt(0)" ::: "memory"); });
    GPH(1, 0,
        if (p1) { stageA(s1,t+1,1); stageA(s1,t+1,3); },
        if (p1) { asm volatile("s_waitcnt vmcnt(2)" ::: "memory"); }
        else    { asm volatile("s_waitcnt vmcnt(0)" ::: "memory"); });
  }
#undef GPH

  if (QKV) {
    unsigned short* qb = (unsigned short*)outp;
    const size_t SZ = (size_t)BH_ * T_ * D_;
    #pragma unroll
    for (int i8 = 0; i8 < 8; ++i8) {
      int mb = m0 + wm*128 + i8*16 + lg*4;
      #pragma unroll
      for (int nf = 0; nf < 2; ++nf) {
        int n = n0 + wn*32 + nf*16 + lr;
        float bv = bias[n];
        int which = n >> 10, c = n & 1023, h = c >> 6, d = c & 63;
        unsigned short* base = qb + (size_t)which * SZ;
        #pragma unroll
        for (int r = 0; r < 4; ++r) {
          int m = mb + r;
          int bb2 = m >> 11, tt = m & 2047;
          float y = acc[i8][nf][r] + bv;
          if (which == 0) y *= QSCALE;
          base[((size_t)(bb2*H_ + h)*T_ + tt)*D_ + d] = f2bf(y);
        }
      }
    }
  } else {
    float* out = (float*)outp;
    #pragma unroll
    for (int i8 = 0; i8 < 8; ++i8) {
      int mb = m0 + wm*128 + i8*16 + lg*4;
      #pragma unroll
      for (int nf = 0; nf < 2; ++nf) {
        int n = n0 + wn*32 + nf*16 + lr;
        float bv = bias[n];
        #pragma unroll
        for (int r = 0; r < 4; ++r)
          out[(size_t)(mb + r)*N + n] = acc[i8][nf][r] + bv;
      }
    }
  }
}

// ---------------- flash attention, 4-wave blocks, one 128-row q-tile each ----------
// (verbatim from round 8 — passed, <85 µs)
__global__ __launch_bounds__(256, 2) void k_attn4(const unsigned short* __restrict__ Qb,
                                                  const unsigned short* __restrict__ Kb,
                                                  const unsigned short* __restrict__ Vb,
                                                  const int* __restrict__ amask,
                                                  unsigned short* __restrict__ Yb) {
  __shared__ __align__(16) char pool[32768];   // [buf][K 8KB | V 8KB]

  const int l = blockIdx.y * 16 + blockIdx.x;
  const int local = l >> 3;                     // 0..127
  const int tq = 15 - (local >> 3);             // q-tile index
  const int bh = (l & 7) * 8 + (local & 7);
  const int bb = bh >> 4, hh = bh & 15;

  const int tid = threadIdx.x;
  const int lane = tid & 63, w = tid >> 6;
  const int hi = lane >> 5, l31 = lane & 31;

  const unsigned short* Qh = Qb + (size_t)bh * (T_*D_);
  const unsigned short* Kh = Kb + (size_t)bh * (T_*D_);
  const unsigned short* Vh = Vb + (size_t)bh * (T_*D_);

  const int kvp = tid & 31, d0v = (tid >> 5) * 8;

  auto stage_load = [&](int i, int b, short8& sv0, short8& sv1, int& nm) {
    const int kv0 = i << 6;
    char* base = pool + b * 16384;
    #pragma unroll
    for (int s = 0; s < 2; ++s) {
      int gi = tid + s * 256;
      int row = gi >> 3, gc = gi & 7;
      gload_lds16(Kh + (size_t)(kv0 + row)*D_ + (gc ^ (row & 7)) * 8, base + gi * 16);
    }
    int kv = kv0 + 2 * kvp;
    sv0 = *reinterpret_cast<const short8*>(Vh + (size_t)kv*D_ + d0v);
    sv1 = *reinterpret_cast<const short8*>(Vh + (size_t)(kv + 1)*D_ + d0v);
    nm = amask[bb*T_ + kv0 + lane];
  };
  auto stage_write = [&](int b, short8 sv0, short8 sv1) {
    unsigned int* vt = (unsigned int*)(pool + b * 16384 + 8192);
    #pragma unroll
    for (int jj = 0; jj < 8; ++jj) {
      int d = d0v + jj;
      unsigned int wd = (unsigned short)sv0[jj] | ((unsigned int)(unsigned short)sv1[jj] << 16);
      vt[d * 32 + (kvp ^ ((d & 7) << 2))] = wd;
    }
  };

  const int nT = 2 * tq + 2;                   // kv-tiles for this q-tile
  const int qbase = tq << 7;
  const int qw = qbase + w * 32;
  const int q  = qw + l31;

  short8 qf[4];
  #pragma unroll
  for (int dt = 0; dt < 4; ++dt)
    qf[dt] = *reinterpret_cast<const short8*>(Qh + (size_t)q*D_ + dt*16 + hi*8);

  f32x16 o0, o1;
  #pragma unroll
  for (int r = 0; r < 16; ++r) { o0[r] = 0.f; o1[r] = 0.f; }
  float mr = -1e30f, ls = 0.f;

  short8 sv0, sv1; int cm;
  stage_load(0, 0, sv0, sv1, cm);
  stage_write(0, sv0, sv1);
  __syncthreads();

  for (int i = 0; i < nT; ++i) {
    const int b = i & 1;
    const bool pf = (i + 1 < nT);
    short8 nv0, nv1; int nm = 0;
    if (pf) stage_load(i + 1, b ^ 1, nv0, nv1, nm);   // EARLY: issue loads
    const int kv0 = i << 6;

    if (kv0 <= qw + 31) {
      const unsigned short* Klb = (const unsigned short*)(pool + b * 16384);
      const char* Vtb = pool + b * 16384 + 8192;

      f32x16 st0, st1;
      #pragma unroll
      for (int r = 0; r < 16; ++r) { st0[r] = 0.f; st1[r] = 0.f; }
      __builtin_amdgcn_s_setprio(1);
      #pragma unroll
      for (int dt = 0; dt < 4; ++dt) {
        int gg = dt * 2 + hi;
        int ra = l31;
        short8 kf0 = *reinterpret_cast<const short8*>(Klb + ra*64 + (gg ^ (ra & 7)) * 8);
        st0 = __builtin_amdgcn_mfma_f32_32x32x16_bf16(kf0, qf[dt], st0, 0, 0, 0);
        int rb = 32 + l31;
        short8 kf1 = *reinterpret_cast<const short8*>(Klb + rb*64 + (gg ^ (rb & 7)) * 8);
        st1 = __builtin_amdgcn_mfma_f32_32x32x16_bf16(kf1, qf[dt], st1, 0, 0, 0);
      }
      __builtin_amdgcn_s_setprio(0);

      if (kv0 + 63 > qw) {
        #pragma unroll
        for (int r = 0; r < 16; ++r) {
          int kvl = (r & 3) + 8 * (r >> 2) + 4 * hi;
          if (kv0 + kvl      > q) st0[r] = -1e30f;
          if (kv0 + 32 + kvl > q) st1[r] = -1e30f;
        }
      }
      unsigned long long mb = __ballot(cm != 0);
      if (mb != ~0ull) {
        #pragma unroll
        for (int r = 0; r < 16; ++r) {
          int kvl = (r & 3) + 8 * (r >> 2) + 4 * hi;
          if (!((mb >> kvl) & 1))        st0[r] = -1e30f;
          if (!((mb >> (kvl + 32)) & 1)) st1[r] = -1e30f;
        }
      }

      // online softmax (exp2 domain), defer-max rescale (T13)
      float mm[8];
      #pragma unroll
      for (int r = 0; r < 8; ++r)
        mm[r] = fmaxf(fmaxf(st0[r], st0[r + 8]), fmaxf(st1[r], st1[r + 8]));
      #pragma unroll
      for (int s = 4; s > 0; s >>= 1)
        #pragma unroll
        for (int r = 0; r < s; ++r) mm[r] = fmaxf(mm[r], mm[r + s]);
      float mo = fmaxf(mm[0], __shfl_xor(mm[0], 32));
      if (!__all(mo <= mr + 8.0f)) {
        float mnew = fmaxf(mr, mo);
        float corr = EXP2(mr - mnew);
        ls *= corr;
        #pragma unroll
        for (int r = 0; r < 16; ++r) { o0[r] *= corr; o1[r] *= corr; }
        mr = mnew;
      }
      float rs = 0.f;
      #pragma unroll
      for (int r = 0; r < 16; ++r) {
        st0[r] = EXP2(st0[r] - mr); rs += st0[r];
        st1[r] = EXP2(st1[r] - mr); rs += st1[r];
      }
      rs += __shfl_xor(rs, 32);
      ls += rs;

      // pack P to bf16 pair-words
      unsigned int pw[2][4][2];
      #pragma unroll
      for (int a = 0; a < 4; ++a) {
        pw[0][a][0] = cvtpk_bf16(st0[4*a],   st0[4*a+1]);
        pw[0][a][1] = cvtpk_bf16(st0[4*a+2], st0[4*a+3]);
        pw[1][a][0] = cvtpk_bf16(st1[4*a],   st1[4*a+1]);
        pw[1][a][1] = cvtpk_bf16(st1[4*a+2], st1[4*a+3]);
      }

      // O^T += V^T x P^T
      #pragma unroll
      for (int kt = 0; kt < 4; ++kt) {
        const int t = kt >> 1, h2 = kt & 1;
        unsigned int send0 = hi ? pw[t][2*h2][0]   : pw[t][2*h2+1][0];
        unsigned int send1 = hi ? pw[t][2*h2][1]   : pw[t][2*h2+1][1];
        unsigned int own0  = hi ? pw[t][2*h2+1][0] : pw[t][2*h2][0];
        unsigned int own1  = hi ? pw[t][2*h2+1][1] : pw[t][2*h2][1];
        unsigned int recv0 = __shfl_xor(send0, 32);
        unsigned int recv1 = __shfl_xor(send1, 32);
        union { unsigned int u[4]; short8 v; } pf2;
        pf2.u[0] = hi ? recv0 : own0;
        pf2.u[1] = hi ? recv1 : own1;
        pf2.u[2] = hi ? own0  : recv0;
        pf2.u[3] = hi ? own1  : recv1;
        int gg = kt * 2 + hi;
        int dA = l31;
        short8 vf0 = *reinterpret_cast<const short8*>(Vtb + dA*128 + ((gg ^ (dA & 7)) * 16));
        int dB = 32 + l31;
        short8 vf1 = *reinterpret_cast<const short8*>(Vtb + dB*128 + ((gg ^ (dB & 7)) * 16));
        __builtin_amdgcn_s_setprio(1);
        o0 = __builtin_amdgcn_mfma_f32_32x32x16_bf16(vf0, pf2.v, o0, 0, 0, 0);
        o1 = __builtin_amdgcn_mfma_f32_32x32x16_bf16(vf1, pf2.v, o1, 0, 0, 0);
        __builtin_amdgcn_s_setprio(0);
      }
    }
    if (pf) { stage_write(b ^ 1, nv0, nv1); cm = nm; }   // LATE: V writes
    __syncthreads();
  }

  // ---- epilogue: direct write (no merge) ----
  float inv = 1.0f / ls;
  size_t rowbase = ((size_t)bb*T_ + q)*C_ + hh*D_;
  #pragma unroll
  for (int a = 0; a < 4; ++a) {
    union { unsigned short h[4]; unsigned long long ll; } y0, y1;
    #pragma unroll
    for (int bq = 0; bq < 4; ++bq) {
      int r = 4*a + bq;
      y0.h[bq] = f2bf(o0[r] * inv);
      y1.h[bq] = f2bf(o1[r] * inv);
    }
    int d0o = 8*a + 4*hi;
    *reinterpret_cast<unsigned long long*>(Yb + rowbase + d0o)      = y0.ll;
    *reinterpret_cast<unsigned long long*>(Yb + rowbase + 32 + d0o) = y1.ll;
  }
}

extern "C" void kernel_launch(void* const* d_in, const int* in_sizes, int n_in,
                              void* d_out, int out_size, void* d_ws, size_t ws_size,
                              hipStream_t stream) {
  const float* x      = (const float*)d_in[0];
  const float* W_attn = (const float*)d_in[1];
  const float* b_attn = (const float*)d_in[2];
  const float* W_proj = (const float*)d_in[3];
  const float* b_proj = (const float*)d_in[4];
  const int*   amask  = (const int*)d_in[5];
  float* out = (float*)d_out;

  char* ws = (char*)d_ws;
  size_t off = 0;
  auto alloc = [&](size_t bytes) { char* p = ws + off; off += (bytes + 255) & ~(size_t)255; return p; };
  unsigned short* xb   = (unsigned short*)alloc((size_t)M_ * C_ * 2);
  unsigned short* Wta  = (unsigned short*)alloc((size_t)3 * C_ * C_ * 2);
  unsigned short* Wtp  = (unsigned short*)alloc((size_t)C_ * C_ * 2);
  unsigned short* qkvb = (unsigned short*)alloc((size_t)3 * BH_ * T_ * D_ * 2);
  unsigned short* Yb   = (unsigned short*)alloc((size_t)M_ * C_ * 2);

  k_cvt<<<(M_ * C_) / 1024, 256, 0, stream>>>(x, xb, M_ * C_);
  k_tr<<<dim3(3*C_/32, C_/32), dim3(32, 8), 0, stream>>>(W_attn, Wta, C_, 3*C_);
  k_tr<<<dim3(C_/32,  C_/32),  dim3(32, 8), 0, stream>>>(W_proj, Wtp, C_, C_);

  k_gemm8<1><<<dim3(3*C_/128, M_/256), 512, 0, stream>>>(xb, Wta, b_attn, qkvb, 3*C_, C_);

  unsigned short* Qb = qkvb;
  unsigned short* Kb = qkvb + (size_t)BH_ * T_ * D_;
  unsigned short* Vb = qkvb + 2 * (size_t)BH_ * T_ * D_;
  k_attn4<<<dim3(16, BH_), 256, 0, stream>>>(Qb, Kb, Vb, amask, Yb);

  k_gemm8<0><<<dim3(C_/128, M_/256), 512, 0, stream>>>(Yb, Wtp, b_proj, out, C_, C_);
}